// Round 6
// baseline (407.753 us; speedup 1.0000x reference)
//
#include <hip/hip_runtime.h>
#include <hip/hip_bf16.h>

// Problem constants
#define DM    1024
#define NH    16
#define DKH   64
#define BB    2
#define SS    2048
#define MROWS (BB*SS)   // 4096

typedef __attribute__((ext_vector_type(8))) short s16x8;
typedef __attribute__((ext_vector_type(4))) float f32x4;
typedef unsigned short u16;

#if __has_builtin(__builtin_amdgcn_exp2f)
#define EXP2(x) __builtin_amdgcn_exp2f(x)
#else
#define EXP2(x) exp2f(x)
#endif

__device__ inline u16 f2b(float f) {
    __hip_bfloat16 h = __float2bfloat16(f);
    return __builtin_bit_cast(u16, h);
}
__device__ inline float b2f(u16 u) {
    return __bfloat162float(__builtin_bit_cast(__hip_bfloat16, u));
}

__device__ inline f32x4 mfma16(s16x8 a, s16x8 b, f32x4 c) {
    return __builtin_amdgcn_mfma_f32_16x16x32_bf16(a, b, c, 0, 0, 0);
}

__device__ inline void gload_lds16(const u16* g, u16* l) {
    __builtin_amdgcn_global_load_lds((const __attribute__((address_space(1))) void*)g,
                                     (__attribute__((address_space(3))) void*)l, 16, 0, 0);
}

// ---------------- prep: fp32 -> bf16 casts ----------------
__global__ void k_prep(const float* __restrict__ x, const float* __restrict__ wq,
                       const float* __restrict__ wk, const float* __restrict__ wv,
                       const float* __restrict__ wo,
                       u16* __restrict__ xb, u16* __restrict__ wqkvb, u16* __restrict__ wob) {
    int64_t i0 = (int64_t)blockIdx.x * blockDim.x + threadIdx.x;
    int64_t strd = (int64_t)gridDim.x * blockDim.x;
    const float4* x4 = (const float4*)x;
    ushort4* xb4 = (ushort4*)xb;
    for (int64_t t = i0; t < (int64_t)MROWS*DM/4; t += strd) {
        float4 v = x4[t];
        xb4[t] = make_ushort4(f2b(v.x), f2b(v.y), f2b(v.z), f2b(v.w));
    }
    const float4* q4 = (const float4*)wq;
    const float4* k4 = (const float4*)wk;
    const float4* v4 = (const float4*)wv;
    const float4* o4 = (const float4*)wo;
    ushort4* w4  = (ushort4*)wqkvb;
    ushort4* wo4 = (ushort4*)wob;
    const int64_t nw4 = (int64_t)DM*DM/4;   // 262144
    for (int64_t t = i0; t < nw4; t += strd) {
        float4 a = q4[t]; w4[t]         = make_ushort4(f2b(a.x), f2b(a.y), f2b(a.z), f2b(a.w));
        float4 b = k4[t]; w4[nw4 + t]   = make_ushort4(f2b(b.x), f2b(b.y), f2b(b.z), f2b(b.w));
        float4 c = v4[t]; w4[2*nw4 + t] = make_ushort4(f2b(c.x), f2b(c.y), f2b(c.z), f2b(c.w));
        float4 d = o4[t]; wo4[t]        = make_ushort4(f2b(d.x), f2b(d.y), f2b(d.z), f2b(d.w));
    }
}

// ---------------- RoPE cos/sin table ----------------
__global__ void k_rope_table(const int* __restrict__ pos, float2* __restrict__ tab) {
    int i = blockIdx.x * blockDim.x + threadIdx.x;  // SS*32 = 65536
    if (i >= SS * 32) return;
    int s = i >> 5, j = i & 31;
    float p = (float)pos[s];
    float freq = powf(10000.0f, -(float)(2 * j) * (1.0f / 64.0f));
    float a = p * freq;
    tab[i] = make_float2(cosf(a), sinf(a));
}

// ---------------- shared 128x128 GEMM mainloop (K=1024, B^T operand) ----------------
__device__ inline void gemm128_loop(const u16* __restrict__ A, const u16* __restrict__ Bt,
                                    int m0, int n0, u16* As, u16* Bs, f32x4 acc[4][4]) {
    const int tid  = threadIdx.x;
    const int lane = tid & 63;
    const int wid  = tid >> 6;
    const int wm = (wid >> 1) << 6;
    const int wn = (wid & 1) << 6;
    const int lr = lane & 15;
    const int lk = (lane >> 4) << 3;

#pragma unroll
    for (int mi = 0; mi < 4; mi++)
#pragma unroll
        for (int ni = 0; ni < 4; ni++) acc[mi][ni] = f32x4{0.f, 0.f, 0.f, 0.f};

    for (int k0 = 0; k0 < 1024; k0 += 32) {
#pragma unroll
        for (int iss = 0; iss < 2; ++iss) {
            int idx = iss * 2048 + tid * 8;
            int row = idx >> 5;
            int col = idx & 31;
            gload_lds16(A  + (int64_t)(m0 + row) * 1024 + (k0 + col), As + idx);
            gload_lds16(Bt + (int64_t)(n0 + row) * 1024 + (k0 + col), Bs + idx);
        }
        __syncthreads();
        s16x8 af[4], bf[4];
#pragma unroll
        for (int mi = 0; mi < 4; mi++)
            af[mi] = *(const s16x8*)(As + (wm + mi * 16 + lr) * 32 + lk);
#pragma unroll
        for (int ni = 0; ni < 4; ni++)
            bf[ni] = *(const s16x8*)(Bs + (wn + ni * 16 + lr) * 32 + lk);
#pragma unroll
        for (int mi = 0; mi < 4; mi++)
#pragma unroll
            for (int ni = 0; ni < 4; ni++)
                acc[mi][ni] = mfma16(af[mi], bf[ni], acc[mi][ni]);
        __syncthreads();
    }
}

// ---------------- QKV projection GEMM with fused RoPE + V-transpose epilogue ----------------
__global__ void __launch_bounds__(256)
k_gemm_qkv(const u16* __restrict__ xb, const u16* __restrict__ wqkvb,
           const float2* __restrict__ tab,
           u16* __restrict__ Qb, u16* __restrict__ Kb, u16* __restrict__ Vt) {
    __shared__ u16 As[4096], Bs[4096];
    int m0 = blockIdx.x * 128, n0 = blockIdx.y * 128;
    f32x4 acc[4][4];
    gemm128_loop(xb, wqkvb, m0, n0, As, Bs, acc);
    const float QSC = 0.18033688011112042f;  // (1/8) * log2(e)
    const int lane = threadIdx.x & 63, wid = threadIdx.x >> 6;
    const int wm = (wid >> 1) << 6, wn = (wid & 1) << 6;
    const int lr = lane & 15, lg = lane >> 4;
    const bool evenlane = (lr & 1) == 0;
#pragma unroll
    for (int mi = 0; mi < 4; mi++) {
        const int gm0 = m0 + wm + mi * 16 + lg * 4;
        const int b = gm0 >> 11;
        const int s0 = gm0 & 2047;
#pragma unroll
        for (int ni = 0; ni < 4; ni++) {
            int gn = n0 + wn + ni * 16 + lr;
            int which = gn >> 10;
            int nn = gn & 1023;
            int h = nn >> 6, d = nn & 63;
            if (which == 2) {
                ushort4 pk;
                pk.x = f2b(acc[mi][ni][0]);
                pk.y = f2b(acc[mi][ni][1]);
                pk.z = f2b(acc[mi][ni][2]);
                pk.w = f2b(acc[mi][ni][3]);
                *(ushort4*)(Vt + ((int64_t)(b * 16 + h)) * (2048 * 64)
                               + (int64_t)d * 2048 + s0) = pk;
            } else {
                u16* dst = (which == 0) ? Qb : Kb;
                float scl = (which == 0) ? QSC : 1.0f;
                int j = d >> 1;
#pragma unroll
                for (int r = 0; r < 4; r++) {
                    float v = acc[mi][ni][r];
                    float partner = __shfl_xor(v, 1, 64);
                    float2 cs = tab[(s0 + r) * 32 + j];
                    float outv = evenlane ? (cs.x * v - cs.y * partner)
                                          : (cs.y * partner + cs.x * v);
                    dst[(((int64_t)(b * 16 + h)) * 2048 + (s0 + r)) * 64 + d] =
                        f2b(outv * scl);
                }
            }
        }
    }
}

// ---------------- causal flash attention, split-KV x2 across blocks ----------------
// ONE wave per block; 32 q-rows; KV tile = 64 keys. Grid 4096 = 32bh x 64chunk x 2seg.
// Partials (unnormalized O, l) accumulate via f32 atomicAdd (2 contributors/address).
__global__ void __launch_bounds__(64, 4)
k_attn(const u16* __restrict__ Q, const u16* __restrict__ K,
       const u16* __restrict__ Vt, float* __restrict__ Oacc, float* __restrict__ lacc) {
    __shared__ char Pbuf[2][4096];   // 32x64 bf16 each, XOR-swizzled
    const int lane = threadIdx.x;
    const int lr = lane & 15;
    const int lg = lane >> 4;
    const int lk = lg * 8;
    const int g     = blockIdx.x >> 5;          // 0..127
    const int bh    = blockIdx.x & 31;          // bh -> XCD bh%8
    const int seg   = g & 1;
    const int chunk = 63 - (g >> 1);            // LPT: heavy chunks first
    const int q0 = chunk << 5;
    const int nfull  = q0 >> 6;                 // diagonal tile index
    const int ntiles = nfull + 1;
    const int half   = ntiles >> 1;
    const int t0   = seg ? half : 0;
    const int nloc = seg ? (ntiles - half) : half;
    if (nloc <= 0) return;
    const int64_t base = (int64_t)bh * (2048 * 64);
    const u16* Qp = Q  + base;
    const u16* Kp = K  + base;
    const u16* Vp = Vt + base;   // [d][s] layout

    s16x8 aq[2][2];
#pragma unroll
    for (int mi = 0; mi < 2; ++mi)
#pragma unroll
        for (int db = 0; db < 2; ++db)
            aq[mi][db] = *(const s16x8*)(Qp + (q0 + mi * 16 + lr) * 64 + db * 32 + lk);

    f32x4 acco[2][4];
    f32x4 accl[2];
#pragma unroll
    for (int mi = 0; mi < 2; ++mi) {
        accl[mi] = f32x4{0.f, 0.f, 0.f, 0.f};
#pragma unroll
        for (int df = 0; df < 4; ++df) acco[mi][df] = f32x4{0.f, 0.f, 0.f, 0.f};
    }
    const s16x8 ones = {(short)0x3F80, (short)0x3F80, (short)0x3F80, (short)0x3F80,
                        (short)0x3F80, (short)0x3F80, (short)0x3F80, (short)0x3F80};
    const int swz = (lr & 7) << 4;
    char* P0 = (char*)&Pbuf[0][0];
    char* P1 = (char*)&Pbuf[1][0];

    // prologue: K and V fragments of tile t0
    s16x8 bk[4][2], bva[2][4], bvb[2][4];
    {
        const int k00 = t0 << 6;
#pragma unroll
        for (int kb = 0; kb < 4; ++kb)
#pragma unroll
            for (int db = 0; db < 2; ++db)
                bk[kb][db] = *(const s16x8*)(Kp + (k00 + kb * 16 + lr) * 64 + db * 32 + lk);
#pragma unroll
        for (int kc = 0; kc < 2; ++kc)
#pragma unroll
            for (int df = 0; df < 4; ++df)
                bva[kc][df] = *(const s16x8*)(Vp + (df * 16 + lr) * 2048 + k00 + kc * 32 + lk);
    }

#define EXP_BLOCK(PDST, DIAG, K0)                                              \
    _Pragma("unroll")                                                          \
    for (int mi = 0; mi < 2; ++mi)                                             \
        _Pragma("unroll")                                                      \
        for (int kb = 0; kb < 4; ++kb)                                         \
            _Pragma("unroll")                                                  \
            for (int r = 0; r < 4; ++r) {                                      \
                int ql = mi * 16 + lg * 4 + r;                                 \
                float sv = sc[mi][kb][r];                                      \
                if (DIAG) {                                                    \
                    int kg = (K0) + kb * 16 + lr;                              \
                    sv = (kg <= q0 + ql) ? sv : -3.0e38f;                      \
                }                                                              \
                float pp = EXP2(sv);                                           \
                int bo = (ql << 7) + ((kb * 16 + lr) << 1);                    \
                *(u16*)((PDST) + (bo ^ ((ql & 7) << 4))) = f2b(pp);            \
            }

#define TILE_BODY(U, PCUR, PPREV, BVO)                                         \
    {                                                                          \
        const int tt  = t0 + (U);                                              \
        const int k0v = tt << 6;                                               \
        f32x4 sc[2][4];                                                        \
        _Pragma("unroll")                                                      \
        for (int mi = 0; mi < 2; ++mi)                                         \
            _Pragma("unroll")                                                  \
            for (int kb = 0; kb < 4; ++kb) {                                   \
                sc[mi][kb] = f32x4{0.f, 0.f, 0.f, 0.f};                        \
                _Pragma("unroll")                                              \
                for (int db = 0; db < 2; ++db)                                 \
                    sc[mi][kb] = mfma16(aq[mi][db], bk[kb][db], sc[mi][kb]);   \
            }                                                                  \
        if ((U) + 1 < nloc) {                                                  \
            const int kn = k0v + 64;                                           \
            _Pragma("unroll")                                                  \
            for (int kb = 0; kb < 4; ++kb)                                     \
                _Pragma("unroll")                                              \
                for (int db = 0; db < 2; ++db)                                 \
                    bk[kb][db] = *(const s16x8*)(Kp + (kn + kb * 16 + lr) * 64 \
                                                 + db * 32 + lk);              \
        }                                                                      \
        s16x8 ap[2][2];                                                        \
        if ((U) > 0) {                                                         \
            _Pragma("unroll")                                                  \
            for (int mi = 0; mi < 2; ++mi)                                     \
                _Pragma("unroll")                                              \
                for (int kc = 0; kc < 2; ++kc) {                               \
                    int ro = ((mi * 16 + lr) << 7) + (kc << 6) + (lg << 4);    \
                    ap[mi][kc] = *(const s16x8*)((PPREV) + (ro ^ swz));        \
                }                                                              \
        }                                                                      \
        if (tt == nfull) { EXP_BLOCK(PCUR, 1, k0v) }                           \
        else             { EXP_BLOCK(PCUR, 0, k0v) }                           \
        if ((U) > 0) {                                                         \
            _Pragma("unroll")                                                  \
            for (int mi = 0; mi < 2; ++mi)                                     \
                _Pragma("unroll")                                              \
                for (int kc = 0; kc < 2; ++kc) {                               \
                    _Pragma("unroll")                                          \
                    for (int df = 0; df < 4; ++df)                             \
                        acco[mi][df] = mfma16(ap[mi][kc], (BVO)[kc][df],       \
                                              acco[mi][df]);                   \
                    accl[mi] = mfma16(ap[mi][kc], ones, accl[mi]);             \
                }                                                              \
        }                                                                      \
        if ((U) + 1 < nloc) {                                                  \
            const int kn = k0v + 64;                                           \
            _Pragma("unroll")                                                  \
            for (int kc = 0; kc < 2; ++kc)                                     \
                _Pragma("unroll")                                              \
                for (int df = 0; df < 4; ++df)                                 \
                    (BVO)[kc][df] = *(const s16x8*)(Vp + (df * 16 + lr) * 2048 \
                                                    + kn + kc * 32 + lk);      \
        }                                                                      \
    }

    for (int u = 0; u < nloc; u += 2) {
        TILE_BODY(u, P0, P1, bvb)
        if (u + 1 < nloc) TILE_BODY(u + 1, P1, P0, bva)
    }

#define PV_FIN(PP, BV)                                                         \
    _Pragma("unroll")                                                          \
    for (int mi = 0; mi < 2; ++mi)                                             \
        _Pragma("unroll")                                                      \
        for (int kc = 0; kc < 2; ++kc) {                                       \
            int ro = ((mi * 16 + lr) << 7) + (kc << 6) + (lg << 4);            \
            s16x8 ap = *(const s16x8*)((PP) + (ro ^ swz));                     \
            _Pragma("unroll")                                                  \
            for (int df = 0; df < 4; ++df)                                     \
                acco[mi][df] = mfma16(ap, (BV)[kc][df], acco[mi][df]);         \
            accl[mi] = mfma16(ap, ones, accl[mi]);                             \
        }

    if ((nloc - 1) & 1) { PV_FIN(P1, bvb) } else { PV_FIN(P0, bva) }
#undef PV_FIN
#undef TILE_BODY
#undef EXP_BLOCK

    // ---- atomic accumulate partials (device-scope f32) ----
    const int b = bh >> 4, h = bh & 15;
#pragma unroll
    for (int mi = 0; mi < 2; ++mi)
#pragma unroll
        for (int df = 0; df < 4; ++df)
#pragma unroll
            for (int r = 0; r < 4; ++r) {
                const int s = q0 + mi * 16 + lg * 4 + r;
                const int d = df * 16 + lr;
                atomicAdd(&Oacc[(((int64_t)(b * 2048 + s)) * 16 + h) * 64 + d],
                          acco[mi][df][r]);
            }
    if (lr == 0) {
#pragma unroll
        for (int mi = 0; mi < 2; ++mi)
#pragma unroll
            for (int r = 0; r < 4; ++r) {
                const int s = q0 + mi * 16 + lg * 4 + r;
                atomicAdd(&lacc[(b * 2048 + s) * 16 + h], accl[mi][r]);
            }
    }
}

// ---------------- combine: Ob = bf16(Oacc / l) ----------------
__global__ void __launch_bounds__(256)
k_combine(const float* __restrict__ Oacc, const float* __restrict__ lacc,
          u16* __restrict__ Ob) {
    int i = (blockIdx.x * 256 + threadIdx.x) * 8;   // grid covers 4096*1024
    float inv = 1.0f / lacc[i >> 6];
    float4 a = *(const float4*)(Oacc + i);
    float4 b = *(const float4*)(Oacc + i + 4);
    ushort4 o0, o1;
    o0.x = f2b(a.x * inv); o0.y = f2b(a.y * inv);
    o0.z = f2b(a.z * inv); o0.w = f2b(a.w * inv);
    o1.x = f2b(b.x * inv); o1.y = f2b(b.y * inv);
    o1.z = f2b(b.z * inv); o1.w = f2b(b.w * inv);
    *(ushort4*)(Ob + i)     = o0;
    *(ushort4*)(Ob + i + 4) = o1;
}

// ---------------- output projection GEMM: M=4096, N=1024, fp32 out ----------------
__global__ void __launch_bounds__(256)
k_gemm_out(const u16* __restrict__ Ob, const u16* __restrict__ wob, float* __restrict__ out) {
    __shared__ u16 As[4096], Bs[4096];
    int m0 = blockIdx.x * 128, n0 = blockIdx.y * 128;
    f32x4 acc[4][4];
    gemm128_loop(Ob, wob, m0, n0, As, Bs, acc);
    const int lane = threadIdx.x & 63, wid = threadIdx.x >> 6;
    const int wm = (wid >> 1) << 6, wn = (wid & 1) << 6;
    const int lr = lane & 15, lg = lane >> 4;
#pragma unroll
    for (int mi = 0; mi < 4; mi++)
#pragma unroll
        for (int ni = 0; ni < 4; ni++) {
            int gn = n0 + wn + ni * 16 + lr;
#pragma unroll
            for (int r = 0; r < 4; r++) {
                int gm = m0 + wm + mi * 16 + lg * 4 + r;
                out[(int64_t)gm * 1024 + gn] = acc[mi][ni][r];
            }
        }
}

extern "C" void kernel_launch(void* const* d_in, const int* in_sizes, int n_in,
                              void* d_out, int out_size, void* d_ws, size_t ws_size,
                              hipStream_t stream) {
    const float* x  = (const float*)d_in[0];
    const int* pos  = (const int*)d_in[1];
    const float* wq = (const float*)d_in[2];
    const float* wk = (const float*)d_in[3];
    const float* wv = (const float*)d_in[4];
    const float* wo = (const float*)d_in[5];
    float* out = (float*)d_out;

    char* w = (char*)d_ws;
    u16* xb    = (u16*)w;    w += (size_t)MROWS * DM * 2;        // 8 MB
    u16* wqkvb = (u16*)w;    w += (size_t)3 * DM * DM * 2;       // 6 MB
    u16* wob   = (u16*)w;    w += (size_t)DM * DM * 2;           // 2 MB
    float2* tab = (float2*)w; w += (size_t)SS * 32 * sizeof(float2); // 512 KB
    u16* Qb = (u16*)w;       w += (size_t)MROWS * DM * 2;        // 8 MB
    u16* Kb = (u16*)w;       w += (size_t)MROWS * DM * 2;        // 8 MB
    u16* Vt = (u16*)w;       w += (size_t)MROWS * DM * 2;        // 8 MB
    u16* Ob = (u16*)w;       w += (size_t)MROWS * DM * 2;        // 8 MB
    float* lacc = (float*)w;                                     // 256 KB
    float* Oacc = out;       // reuse d_out as f32 scratch accumulator

    hipMemsetAsync(Oacc, 0, (size_t)MROWS * DM * sizeof(float), stream);
    hipMemsetAsync(lacc, 0, (size_t)MROWS * NH * sizeof(float), stream);
    k_prep<<<dim3(1024), dim3(256), 0, stream>>>(x, wq, wk, wv, wo, xb, wqkvb, wob);
    k_rope_table<<<dim3(256), dim3(256), 0, stream>>>(pos, tab);
    k_gemm_qkv<<<dim3(32, 24), dim3(256), 0, stream>>>(xb, wqkvb, tab, Qb, Kb, Vt);
    k_attn<<<dim3(4096), dim3(64), 0, stream>>>(Qb, Kb, Vt, Oacc, lacc);
    k_combine<<<dim3(MROWS * DM / 2048), dim3(256), 0, stream>>>(Oacc, lacc, Ob);
    k_gemm_out<<<dim3(32, 8), dim3(256), 0, stream>>>(Ob, wob, out);
}

// Round 7
// 264.120 us; speedup vs baseline: 1.5438x; 1.5438x over previous
//
#include <hip/hip_runtime.h>
#include <hip/hip_bf16.h>

// Problem constants
#define DM    1024
#define NH    16
#define DKH   64
#define BB    2
#define SS    2048
#define MROWS (BB*SS)   // 4096

typedef __attribute__((ext_vector_type(8))) short s16x8;
typedef __attribute__((ext_vector_type(4))) float f32x4;
typedef unsigned short u16;

#if __has_builtin(__builtin_amdgcn_exp2f)
#define EXP2(x) __builtin_amdgcn_exp2f(x)
#else
#define EXP2(x) exp2f(x)
#endif

__device__ inline u16 f2b(float f) {
    __hip_bfloat16 h = __float2bfloat16(f);
    return __builtin_bit_cast(u16, h);
}
__device__ inline float b2f(u16 u) {
    return __bfloat162float(__builtin_bit_cast(__hip_bfloat16, u));
}

__device__ inline f32x4 mfma16(s16x8 a, s16x8 b, f32x4 c) {
    return __builtin_amdgcn_mfma_f32_16x16x32_bf16(a, b, c, 0, 0, 0);
}

__device__ inline void gload_lds16(const u16* g, u16* l) {
    __builtin_amdgcn_global_load_lds((const __attribute__((address_space(1))) void*)g,
                                     (__attribute__((address_space(3))) void*)l, 16, 0, 0);
}

// ---------------- prep: fp32 -> bf16 casts ----------------
__global__ void k_prep(const float* __restrict__ x, const float* __restrict__ wq,
                       const float* __restrict__ wk, const float* __restrict__ wv,
                       const float* __restrict__ wo,
                       u16* __restrict__ xb, u16* __restrict__ wqkvb, u16* __restrict__ wob) {
    int64_t i0 = (int64_t)blockIdx.x * blockDim.x + threadIdx.x;
    int64_t strd = (int64_t)gridDim.x * blockDim.x;
    const float4* x4 = (const float4*)x;
    ushort4* xb4 = (ushort4*)xb;
    for (int64_t t = i0; t < (int64_t)MROWS*DM/4; t += strd) {
        float4 v = x4[t];
        xb4[t] = make_ushort4(f2b(v.x), f2b(v.y), f2b(v.z), f2b(v.w));
    }
    const float4* q4 = (const float4*)wq;
    const float4* k4 = (const float4*)wk;
    const float4* v4 = (const float4*)wv;
    const float4* o4 = (const float4*)wo;
    ushort4* w4  = (ushort4*)wqkvb;
    ushort4* wo4 = (ushort4*)wob;
    const int64_t nw4 = (int64_t)DM*DM/4;   // 262144
    for (int64_t t = i0; t < nw4; t += strd) {
        float4 a = q4[t]; w4[t]         = make_ushort4(f2b(a.x), f2b(a.y), f2b(a.z), f2b(a.w));
        float4 b = k4[t]; w4[nw4 + t]   = make_ushort4(f2b(b.x), f2b(b.y), f2b(b.z), f2b(b.w));
        float4 c = v4[t]; w4[2*nw4 + t] = make_ushort4(f2b(c.x), f2b(c.y), f2b(c.z), f2b(c.w));
        float4 d = o4[t]; wo4[t]        = make_ushort4(f2b(d.x), f2b(d.y), f2b(d.z), f2b(d.w));
    }
}

// ---------------- RoPE cos/sin table ----------------
__global__ void k_rope_table(const int* __restrict__ pos, float2* __restrict__ tab) {
    int i = blockIdx.x * blockDim.x + threadIdx.x;  // SS*32 = 65536
    if (i >= SS * 32) return;
    int s = i >> 5, j = i & 31;
    float p = (float)pos[s];
    float freq = powf(10000.0f, -(float)(2 * j) * (1.0f / 64.0f));
    float a = p * freq;
    tab[i] = make_float2(cosf(a), sinf(a));
}

// ---------------- shared 128x128 GEMM mainloop (K=1024, B^T operand) ----------------
__device__ inline void gemm128_loop(const u16* __restrict__ A, const u16* __restrict__ Bt,
                                    int m0, int n0, u16* As, u16* Bs, f32x4 acc[4][4]) {
    const int tid  = threadIdx.x;
    const int lane = tid & 63;
    const int wid  = tid >> 6;
    const int wm = (wid >> 1) << 6;
    const int wn = (wid & 1) << 6;
    const int lr = lane & 15;
    const int lk = (lane >> 4) << 3;

#pragma unroll
    for (int mi = 0; mi < 4; mi++)
#pragma unroll
        for (int ni = 0; ni < 4; ni++) acc[mi][ni] = f32x4{0.f, 0.f, 0.f, 0.f};

    for (int k0 = 0; k0 < 1024; k0 += 32) {
#pragma unroll
        for (int iss = 0; iss < 2; ++iss) {
            int idx = iss * 2048 + tid * 8;
            int row = idx >> 5;
            int col = idx & 31;
            gload_lds16(A  + (int64_t)(m0 + row) * 1024 + (k0 + col), As + idx);
            gload_lds16(Bt + (int64_t)(n0 + row) * 1024 + (k0 + col), Bs + idx);
        }
        __syncthreads();
        s16x8 af[4], bf[4];
#pragma unroll
        for (int mi = 0; mi < 4; mi++)
            af[mi] = *(const s16x8*)(As + (wm + mi * 16 + lr) * 32 + lk);
#pragma unroll
        for (int ni = 0; ni < 4; ni++)
            bf[ni] = *(const s16x8*)(Bs + (wn + ni * 16 + lr) * 32 + lk);
#pragma unroll
        for (int mi = 0; mi < 4; mi++)
#pragma unroll
            for (int ni = 0; ni < 4; ni++)
                acc[mi][ni] = mfma16(af[mi], bf[ni], acc[mi][ni]);
        __syncthreads();
    }
}

// ---------------- QKV projection GEMM with fused RoPE + V-transpose epilogue ----------------
__global__ void __launch_bounds__(256)
k_gemm_qkv(const u16* __restrict__ xb, const u16* __restrict__ wqkvb,
           const float2* __restrict__ tab,
           u16* __restrict__ Qb, u16* __restrict__ Kb, u16* __restrict__ Vt) {
    __shared__ u16 As[4096], Bs[4096];
    int m0 = blockIdx.x * 128, n0 = blockIdx.y * 128;
    f32x4 acc[4][4];
    gemm128_loop(xb, wqkvb, m0, n0, As, Bs, acc);
    const float QSC = 0.18033688011112042f;  // (1/8) * log2(e)
    const int lane = threadIdx.x & 63, wid = threadIdx.x >> 6;
    const int wm = (wid >> 1) << 6, wn = (wid & 1) << 6;
    const int lr = lane & 15, lg = lane >> 4;
    const bool evenlane = (lr & 1) == 0;
#pragma unroll
    for (int mi = 0; mi < 4; mi++) {
        const int gm0 = m0 + wm + mi * 16 + lg * 4;
        const int b = gm0 >> 11;
        const int s0 = gm0 & 2047;
#pragma unroll
        for (int ni = 0; ni < 4; ni++) {
            int gn = n0 + wn + ni * 16 + lr;
            int which = gn >> 10;
            int nn = gn & 1023;
            int h = nn >> 6, d = nn & 63;
            if (which == 2) {
                ushort4 pk;
                pk.x = f2b(acc[mi][ni][0]);
                pk.y = f2b(acc[mi][ni][1]);
                pk.z = f2b(acc[mi][ni][2]);
                pk.w = f2b(acc[mi][ni][3]);
                *(ushort4*)(Vt + ((int64_t)(b * 16 + h)) * (2048 * 64)
                               + (int64_t)d * 2048 + s0) = pk;
            } else {
                u16* dst = (which == 0) ? Qb : Kb;
                float scl = (which == 0) ? QSC : 1.0f;
                int j = d >> 1;
#pragma unroll
                for (int r = 0; r < 4; r++) {
                    float v = acc[mi][ni][r];
                    float partner = __shfl_xor(v, 1, 64);
                    float2 cs = tab[(s0 + r) * 32 + j];
                    float outv = evenlane ? (cs.x * v - cs.y * partner)
                                          : (cs.y * partner + cs.x * v);
                    dst[(((int64_t)(b * 16 + h)) * 2048 + (s0 + r)) * 64 + d] =
                        f2b(outv * scl);
                }
            }
        }
    }
}

// ---------------- causal flash attention, intra-block split-KV x2 ----------------
// 2 waves per block on the SAME 32-row q-chunk; wave0 handles KV tiles [0,half),
// wave1 [half,ntiles) (incl. diagonal). Max-free softmax => partials sum linearly;
// combine via one LDS exchange (no atomics, no global traffic).
// LPT dispatch + bh->XCD affinity.
__global__ void __launch_bounds__(128, 4)
k_attn(const u16* __restrict__ Q, const u16* __restrict__ K,
       const u16* __restrict__ Vt, u16* __restrict__ O) {
    __shared__ char Pbuf[2][4096];   // per-wave 32x64 bf16 P, XOR-swizzled
    __shared__ float lbuf[32];
    const int tid  = threadIdx.x;
    const int lane = tid & 63;
    const int wid  = tid >> 6;                  // 0..1 = KV segment
    const int lr = lane & 15;
    const int lg = lane >> 4;
    const int lk = lg * 8;
    const int bh    = blockIdx.x & 31;          // bh -> XCD bh%8
    const int chunk = 63 - (blockIdx.x >> 5);   // LPT: heavy chunks first
    const int q0 = chunk << 5;
    const int nfull  = q0 >> 6;                 // diagonal tile index
    const int ntiles = nfull + 1;
    const int half   = ntiles >> 1;
    const int t0   = wid ? half : 0;
    const int tend = wid ? ntiles : half;       // exclusive
    const int64_t base = (int64_t)bh * (2048 * 64);
    const u16* Qp = Q  + base;
    const u16* Kp = K  + base;
    const u16* Vp = Vt + base;   // [d][s] layout

    // Q fragments (already scaled by 0.125*log2e in rope)
    s16x8 aq[2][2];
#pragma unroll
    for (int mi = 0; mi < 2; ++mi)
#pragma unroll
        for (int db = 0; db < 2; ++db)
            aq[mi][db] = *(const s16x8*)(Qp + (q0 + mi * 16 + lr) * 64 + db * 32 + lk);

    f32x4 acco[2][4];
    f32x4 accl[2];
#pragma unroll
    for (int mi = 0; mi < 2; ++mi) {
        accl[mi] = f32x4{0.f, 0.f, 0.f, 0.f};
#pragma unroll
        for (int df = 0; df < 4; ++df) acco[mi][df] = f32x4{0.f, 0.f, 0.f, 0.f};
    }
    const s16x8 ones = {(short)0x3F80, (short)0x3F80, (short)0x3F80, (short)0x3F80,
                        (short)0x3F80, (short)0x3F80, (short)0x3F80, (short)0x3F80};
    const int swz = (lr & 7) << 4;
    char* PwB = &Pbuf[wid][0];

    for (int t = t0; t < tend; ++t) {
        const int k0 = t << 6;
        // V fragments first (used last -> latency hidden under QK^T + softmax)
        s16x8 bv[2][4];
#pragma unroll
        for (int kc = 0; kc < 2; ++kc)
#pragma unroll
            for (int df = 0; df < 4; ++df)
                bv[kc][df] = *(const s16x8*)(Vp + (df * 16 + lr) * 2048 + k0 + kc * 32 + lk);
        // K fragments
        s16x8 bk[4][2];
#pragma unroll
        for (int kb = 0; kb < 4; ++kb)
#pragma unroll
            for (int db = 0; db < 2; ++db)
                bk[kb][db] = *(const s16x8*)(Kp + (k0 + kb * 16 + lr) * 64 + db * 32 + lk);
        // QK^T
        f32x4 sc[2][4];
#pragma unroll
        for (int mi = 0; mi < 2; ++mi)
#pragma unroll
            for (int kb = 0; kb < 4; ++kb) {
                sc[mi][kb] = f32x4{0.f, 0.f, 0.f, 0.f};
#pragma unroll
                for (int db = 0; db < 2; ++db)
                    sc[mi][kb] = mfma16(aq[mi][db], bk[kb][db], sc[mi][kb]);
            }
        // exp2 + P write (mask only on diagonal tile, which lives in wave1)
        if (t == nfull) {
#pragma unroll
            for (int mi = 0; mi < 2; ++mi)
#pragma unroll
                for (int kb = 0; kb < 4; ++kb)
#pragma unroll
                    for (int r = 0; r < 4; ++r) {
                        int ql = mi * 16 + lg * 4 + r;
                        int kg = k0 + kb * 16 + lr;
                        float sv = (kg <= q0 + ql) ? sc[mi][kb][r] : -3.0e38f;
                        float pp = EXP2(sv);
                        int bo = (ql << 7) + ((kb * 16 + lr) << 1);
                        *(u16*)(PwB + (bo ^ ((ql & 7) << 4))) = f2b(pp);
                    }
        } else {
#pragma unroll
            for (int mi = 0; mi < 2; ++mi)
#pragma unroll
                for (int kb = 0; kb < 4; ++kb)
#pragma unroll
                    for (int r = 0; r < 4; ++r) {
                        int ql = mi * 16 + lg * 4 + r;
                        float pp = EXP2(sc[mi][kb][r]);
                        int bo = (ql << 7) + ((kb * 16 + lr) << 1);
                        *(u16*)(PwB + (bo ^ ((ql & 7) << 4))) = f2b(pp);
                    }
        }
        asm volatile("s_waitcnt lgkmcnt(0)" ::: "memory");
        // PV + row-sum via all-ones MFMA
#pragma unroll
        for (int mi = 0; mi < 2; ++mi)
#pragma unroll
            for (int kc = 0; kc < 2; ++kc) {
                int ro = ((mi * 16 + lr) << 7) + (kc << 6) + (lg << 4);
                s16x8 ap = *(const s16x8*)(PwB + (ro ^ swz));
#pragma unroll
                for (int df = 0; df < 4; ++df)
                    acco[mi][df] = mfma16(ap, bv[kc][df], acco[mi][df]);
                accl[mi] = mfma16(ap, ones, accl[mi]);
            }
    }

    // ---- intra-block combine: wave1 -> LDS, wave0 adds + normalizes + stores ----
    float* ob = (float*)&Pbuf[0][0];   // 32x64 f32 = 8KB (both P buffers, now dead)
    __syncthreads();
    if (wid == 1) {
#pragma unroll
        for (int mi = 0; mi < 2; ++mi) {
#pragma unroll
            for (int df = 0; df < 4; ++df)
#pragma unroll
                for (int r = 0; r < 4; ++r)
                    ob[(mi * 16 + lg * 4 + r) * 64 + df * 16 + lr] = acco[mi][df][r];
            if (lr == 0)
#pragma unroll
                for (int r = 0; r < 4; ++r)
                    lbuf[mi * 16 + lg * 4 + r] = accl[mi][r];
        }
    }
    __syncthreads();
    if (wid == 0) {
        const int b = bh >> 4, h = bh & 15;
#pragma unroll
        for (int mi = 0; mi < 2; ++mi) {
            float inv[4];
#pragma unroll
            for (int r = 0; r < 4; ++r)
                inv[r] = 1.0f / (accl[mi][r] + lbuf[mi * 16 + lg * 4 + r]);
#pragma unroll
            for (int df = 0; df < 4; ++df)
#pragma unroll
                for (int r = 0; r < 4; ++r) {
                    const int s = q0 + mi * 16 + lg * 4 + r;
                    const int d = df * 16 + lr;
                    float val = acco[mi][df][r] + ob[(mi * 16 + lg * 4 + r) * 64 + d];
                    O[(((int64_t)(b * 2048 + s)) * 16 + h) * 64 + d] = f2b(val * inv[r]);
                }
        }
    }
}

// ---------------- output projection GEMM: M=4096, N=1024, fp32 out ----------------
__global__ void __launch_bounds__(256)
k_gemm_out(const u16* __restrict__ Ob, const u16* __restrict__ wob, float* __restrict__ out) {
    __shared__ u16 As[4096], Bs[4096];
    int m0 = blockIdx.x * 128, n0 = blockIdx.y * 128;
    f32x4 acc[4][4];
    gemm128_loop(Ob, wob, m0, n0, As, Bs, acc);
    const int lane = threadIdx.x & 63, wid = threadIdx.x >> 6;
    const int wm = (wid >> 1) << 6, wn = (wid & 1) << 6;
    const int lr = lane & 15, lg = lane >> 4;
#pragma unroll
    for (int mi = 0; mi < 4; mi++)
#pragma unroll
        for (int ni = 0; ni < 4; ni++) {
            int gn = n0 + wn + ni * 16 + lr;
#pragma unroll
            for (int r = 0; r < 4; r++) {
                int gm = m0 + wm + mi * 16 + lg * 4 + r;
                out[(int64_t)gm * 1024 + gn] = acc[mi][ni][r];
            }
        }
}

extern "C" void kernel_launch(void* const* d_in, const int* in_sizes, int n_in,
                              void* d_out, int out_size, void* d_ws, size_t ws_size,
                              hipStream_t stream) {
    const float* x  = (const float*)d_in[0];
    const int* pos  = (const int*)d_in[1];
    const float* wq = (const float*)d_in[2];
    const float* wk = (const float*)d_in[3];
    const float* wv = (const float*)d_in[4];
    const float* wo = (const float*)d_in[5];
    float* out = (float*)d_out;

    char* w = (char*)d_ws;
    u16* xb    = (u16*)w;    w += (size_t)MROWS * DM * 2;        // 8 MB
    u16* wqkvb = (u16*)w;    w += (size_t)3 * DM * DM * 2;       // 6 MB
    u16* wob   = (u16*)w;    w += (size_t)DM * DM * 2;           // 2 MB
    float2* tab = (float2*)w; w += (size_t)SS * 32 * sizeof(float2); // 512 KB
    u16* Qb = (u16*)w;       w += (size_t)MROWS * DM * 2;        // 8 MB
    u16* Kb = (u16*)w;       w += (size_t)MROWS * DM * 2;        // 8 MB
    u16* Vt = (u16*)w;       w += (size_t)MROWS * DM * 2;        // 8 MB
    u16* Ob = (u16*)w;                                           // 8 MB

    k_prep<<<dim3(1024), dim3(256), 0, stream>>>(x, wq, wk, wv, wo, xb, wqkvb, wob);
    k_rope_table<<<dim3(256), dim3(256), 0, stream>>>(pos, tab);
    k_gemm_qkv<<<dim3(32, 24), dim3(256), 0, stream>>>(xb, wqkvb, tab, Qb, Kb, Vt);
    k_attn<<<dim3(2048), dim3(128), 0, stream>>>(Qb, Kb, Vt, Ob);
    k_gemm_out<<<dim3(32, 8), dim3(256), 0, stream>>>(Ob, wob, out);
}

// Round 8
// 143.428 us; speedup vs baseline: 2.8429x; 1.8415x over previous
//
#include <hip/hip_runtime.h>
#include <hip/hip_bf16.h>

// Problem constants
#define DM    1024
#define NH    16
#define DKH   64
#define BB    2
#define SS    2048
#define MROWS (BB*SS)   // 4096

typedef __attribute__((ext_vector_type(8))) short s16x8;
typedef __attribute__((ext_vector_type(4))) float f32x4;
typedef unsigned short u16;

#if __has_builtin(__builtin_amdgcn_exp2f)
#define EXP2(x) __builtin_amdgcn_exp2f(x)
#else
#define EXP2(x) exp2f(x)
#endif

__device__ inline u16 f2b(float f) {
    __hip_bfloat16 h = __float2bfloat16(f);
    return __builtin_bit_cast(u16, h);
}
__device__ inline float b2f(u16 u) {
    return __bfloat162float(__builtin_bit_cast(__hip_bfloat16, u));
}

__device__ inline f32x4 mfma16(s16x8 a, s16x8 b, f32x4 c) {
    return __builtin_amdgcn_mfma_f32_16x16x32_bf16(a, b, c, 0, 0, 0);
}

__device__ inline void gload_lds16(const u16* g, u16* l) {
    __builtin_amdgcn_global_load_lds((const __attribute__((address_space(1))) void*)g,
                                     (__attribute__((address_space(3))) void*)l, 16, 0, 0);
}

// ---------------- prep: fp32 -> bf16 casts ----------------
__global__ void k_prep(const float* __restrict__ x, const float* __restrict__ wq,
                       const float* __restrict__ wk, const float* __restrict__ wv,
                       const float* __restrict__ wo,
                       u16* __restrict__ xb, u16* __restrict__ wqkvb, u16* __restrict__ wob) {
    int64_t i0 = (int64_t)blockIdx.x * blockDim.x + threadIdx.x;
    int64_t strd = (int64_t)gridDim.x * blockDim.x;
    const float4* x4 = (const float4*)x;
    ushort4* xb4 = (ushort4*)xb;
    for (int64_t t = i0; t < (int64_t)MROWS*DM/4; t += strd) {
        float4 v = x4[t];
        xb4[t] = make_ushort4(f2b(v.x), f2b(v.y), f2b(v.z), f2b(v.w));
    }
    const float4* q4 = (const float4*)wq;
    const float4* k4 = (const float4*)wk;
    const float4* v4 = (const float4*)wv;
    const float4* o4 = (const float4*)wo;
    ushort4* w4  = (ushort4*)wqkvb;
    ushort4* wo4 = (ushort4*)wob;
    const int64_t nw4 = (int64_t)DM*DM/4;   // 262144
    for (int64_t t = i0; t < nw4; t += strd) {
        float4 a = q4[t]; w4[t]         = make_ushort4(f2b(a.x), f2b(a.y), f2b(a.z), f2b(a.w));
        float4 b = k4[t]; w4[nw4 + t]   = make_ushort4(f2b(b.x), f2b(b.y), f2b(b.z), f2b(b.w));
        float4 c = v4[t]; w4[2*nw4 + t] = make_ushort4(f2b(c.x), f2b(c.y), f2b(c.z), f2b(c.w));
        float4 d = o4[t]; wo4[t]        = make_ushort4(f2b(d.x), f2b(d.y), f2b(d.z), f2b(d.w));
    }
}

// ---------------- RoPE cos/sin table ----------------
__global__ void k_rope_table(const int* __restrict__ pos, float2* __restrict__ tab) {
    int i = blockIdx.x * blockDim.x + threadIdx.x;  // SS*32 = 65536
    if (i >= SS * 32) return;
    int s = i >> 5, j = i & 31;
    float p = (float)pos[s];
    float freq = powf(10000.0f, -(float)(2 * j) * (1.0f / 64.0f));
    float a = p * freq;
    tab[i] = make_float2(cosf(a), sinf(a));
}

// ---------------- shared 128x128 GEMM mainloop (K=1024, B^T operand) ----------------
__device__ inline void gemm128_loop(const u16* __restrict__ A, const u16* __restrict__ Bt,
                                    int m0, int n0, u16* As, u16* Bs, f32x4 acc[4][4]) {
    const int tid  = threadIdx.x;
    const int lane = tid & 63;
    const int wid  = tid >> 6;
    const int wm = (wid >> 1) << 6;
    const int wn = (wid & 1) << 6;
    const int lr = lane & 15;
    const int lk = (lane >> 4) << 3;

#pragma unroll
    for (int mi = 0; mi < 4; mi++)
#pragma unroll
        for (int ni = 0; ni < 4; ni++) acc[mi][ni] = f32x4{0.f, 0.f, 0.f, 0.f};

    for (int k0 = 0; k0 < 1024; k0 += 32) {
#pragma unroll
        for (int iss = 0; iss < 2; ++iss) {
            int idx = iss * 2048 + tid * 8;
            int row = idx >> 5;
            int col = idx & 31;
            gload_lds16(A  + (int64_t)(m0 + row) * 1024 + (k0 + col), As + idx);
            gload_lds16(Bt + (int64_t)(n0 + row) * 1024 + (k0 + col), Bs + idx);
        }
        __syncthreads();
        s16x8 af[4], bf[4];
#pragma unroll
        for (int mi = 0; mi < 4; mi++)
            af[mi] = *(const s16x8*)(As + (wm + mi * 16 + lr) * 32 + lk);
#pragma unroll
        for (int ni = 0; ni < 4; ni++)
            bf[ni] = *(const s16x8*)(Bs + (wn + ni * 16 + lr) * 32 + lk);
#pragma unroll
        for (int mi = 0; mi < 4; mi++)
#pragma unroll
            for (int ni = 0; ni < 4; ni++)
                acc[mi][ni] = mfma16(af[mi], bf[ni], acc[mi][ni]);
        __syncthreads();
    }
}

// ---------------- QKV projection GEMM with fused RoPE + V-transpose epilogue ----------------
__global__ void __launch_bounds__(256)
k_gemm_qkv(const u16* __restrict__ xb, const u16* __restrict__ wqkvb,
           const float2* __restrict__ tab,
           u16* __restrict__ Qb, u16* __restrict__ Kb, u16* __restrict__ Vt) {
    __shared__ u16 As[4096], Bs[4096];
    int m0 = blockIdx.x * 128, n0 = blockIdx.y * 128;
    f32x4 acc[4][4];
    gemm128_loop(xb, wqkvb, m0, n0, As, Bs, acc);
    const float QSC = 0.18033688011112042f;  // (1/8) * log2(e)
    const int lane = threadIdx.x & 63, wid = threadIdx.x >> 6;
    const int wm = (wid >> 1) << 6, wn = (wid & 1) << 6;
    const int lr = lane & 15, lg = lane >> 4;
    const bool evenlane = (lr & 1) == 0;
#pragma unroll
    for (int mi = 0; mi < 4; mi++) {
        const int gm0 = m0 + wm + mi * 16 + lg * 4;
        const int b = gm0 >> 11;
        const int s0 = gm0 & 2047;
#pragma unroll
        for (int ni = 0; ni < 4; ni++) {
            int gn = n0 + wn + ni * 16 + lr;
            int which = gn >> 10;
            int nn = gn & 1023;
            int h = nn >> 6, d = nn & 63;
            if (which == 2) {
                ushort4 pk;
                pk.x = f2b(acc[mi][ni][0]);
                pk.y = f2b(acc[mi][ni][1]);
                pk.z = f2b(acc[mi][ni][2]);
                pk.w = f2b(acc[mi][ni][3]);
                *(ushort4*)(Vt + ((int64_t)(b * 16 + h)) * (2048 * 64)
                               + (int64_t)d * 2048 + s0) = pk;
            } else {
                u16* dst = (which == 0) ? Qb : Kb;
                float scl = (which == 0) ? QSC : 1.0f;
                int j = d >> 1;
#pragma unroll
                for (int r = 0; r < 4; r++) {
                    float v = acc[mi][ni][r];
                    float partner = __shfl_xor(v, 1, 64);
                    float2 cs = tab[(s0 + r) * 32 + j];
                    float outv = evenlane ? (cs.x * v - cs.y * partner)
                                          : (cs.y * partner + cs.x * v);
                    dst[(((int64_t)(b * 16 + h)) * 2048 + (s0 + r)) * 64 + d] =
                        f2b(outv * scl);
                }
            }
        }
    }
}

// ---------------- causal flash attention, intra-block split-KV x2 ----------------
// 2 waves per block on the SAME 32-row q-chunk; wave0 handles KV tiles [0,half),
// wave1 [half,ntiles) (incl. diagonal). Max-free softmax => partials sum linearly;
// combine via one LDS exchange (no atomics, no global traffic).
// NOTE: no min-occupancy launch_bounds arg — (128,4) forced VGPR=64 and massive
// scratch spills (R7: FETCH 254MB, 208us). Natural allocation ~116-130 VGPR.
__global__ void __launch_bounds__(128)
k_attn(const u16* __restrict__ Q, const u16* __restrict__ K,
       const u16* __restrict__ Vt, u16* __restrict__ O) {
    __shared__ char Pbuf[2][4096];   // per-wave 32x64 bf16 P, XOR-swizzled
    __shared__ float lbuf[32];
    const int tid  = threadIdx.x;
    const int lane = tid & 63;
    const int wid  = tid >> 6;                  // 0..1 = KV segment
    const int lr = lane & 15;
    const int lg = lane >> 4;
    const int lk = lg * 8;
    const int bh    = blockIdx.x & 31;          // bh -> XCD bh%8
    const int chunk = 63 - (blockIdx.x >> 5);   // LPT: heavy chunks first
    const int q0 = chunk << 5;
    const int nfull  = q0 >> 6;                 // diagonal tile index
    const int ntiles = nfull + 1;
    const int half   = ntiles >> 1;
    const int t0   = wid ? half : 0;
    const int tend = wid ? ntiles : half;       // exclusive
    const int64_t base = (int64_t)bh * (2048 * 64);
    const u16* Qp = Q  + base;
    const u16* Kp = K  + base;
    const u16* Vp = Vt + base;   // [d][s] layout

    // Q fragments (already scaled by 0.125*log2e in rope)
    s16x8 aq[2][2];
#pragma unroll
    for (int mi = 0; mi < 2; ++mi)
#pragma unroll
        for (int db = 0; db < 2; ++db)
            aq[mi][db] = *(const s16x8*)(Qp + (q0 + mi * 16 + lr) * 64 + db * 32 + lk);

    f32x4 acco[2][4];
    f32x4 accl[2];
#pragma unroll
    for (int mi = 0; mi < 2; ++mi) {
        accl[mi] = f32x4{0.f, 0.f, 0.f, 0.f};
#pragma unroll
        for (int df = 0; df < 4; ++df) acco[mi][df] = f32x4{0.f, 0.f, 0.f, 0.f};
    }
    const s16x8 ones = {(short)0x3F80, (short)0x3F80, (short)0x3F80, (short)0x3F80,
                        (short)0x3F80, (short)0x3F80, (short)0x3F80, (short)0x3F80};
    const int swz = (lr & 7) << 4;
    char* PwB = &Pbuf[wid][0];

    for (int t = t0; t < tend; ++t) {
        const int k0 = t << 6;
        // V fragments first (used last -> latency hidden under QK^T + softmax)
        s16x8 bv[2][4];
#pragma unroll
        for (int kc = 0; kc < 2; ++kc)
#pragma unroll
            for (int df = 0; df < 4; ++df)
                bv[kc][df] = *(const s16x8*)(Vp + (df * 16 + lr) * 2048 + k0 + kc * 32 + lk);
        // K fragments
        s16x8 bk[4][2];
#pragma unroll
        for (int kb = 0; kb < 4; ++kb)
#pragma unroll
            for (int db = 0; db < 2; ++db)
                bk[kb][db] = *(const s16x8*)(Kp + (k0 + kb * 16 + lr) * 64 + db * 32 + lk);
        // QK^T
        f32x4 sc[2][4];
        __builtin_amdgcn_s_setprio(1);
#pragma unroll
        for (int mi = 0; mi < 2; ++mi)
#pragma unroll
            for (int kb = 0; kb < 4; ++kb) {
                sc[mi][kb] = f32x4{0.f, 0.f, 0.f, 0.f};
#pragma unroll
                for (int db = 0; db < 2; ++db)
                    sc[mi][kb] = mfma16(aq[mi][db], bk[kb][db], sc[mi][kb]);
            }
        __builtin_amdgcn_s_setprio(0);
        // exp2 + P write (mask only on diagonal tile, which lives in wave1)
        if (t == nfull) {
#pragma unroll
            for (int mi = 0; mi < 2; ++mi)
#pragma unroll
                for (int kb = 0; kb < 4; ++kb)
#pragma unroll
                    for (int r = 0; r < 4; ++r) {
                        int ql = mi * 16 + lg * 4 + r;
                        int kg = k0 + kb * 16 + lr;
                        float sv = (kg <= q0 + ql) ? sc[mi][kb][r] : -3.0e38f;
                        float pp = EXP2(sv);
                        int bo = (ql << 7) + ((kb * 16 + lr) << 1);
                        *(u16*)(PwB + (bo ^ ((ql & 7) << 4))) = f2b(pp);
                    }
        } else {
#pragma unroll
            for (int mi = 0; mi < 2; ++mi)
#pragma unroll
                for (int kb = 0; kb < 4; ++kb)
#pragma unroll
                    for (int r = 0; r < 4; ++r) {
                        int ql = mi * 16 + lg * 4 + r;
                        float pp = EXP2(sc[mi][kb][r]);
                        int bo = (ql << 7) + ((kb * 16 + lr) << 1);
                        *(u16*)(PwB + (bo ^ ((ql & 7) << 4))) = f2b(pp);
                    }
        }
        asm volatile("s_waitcnt lgkmcnt(0)" ::: "memory");
        // PV + row-sum via all-ones MFMA
        __builtin_amdgcn_s_setprio(1);
#pragma unroll
        for (int mi = 0; mi < 2; ++mi)
#pragma unroll
            for (int kc = 0; kc < 2; ++kc) {
                int ro = ((mi * 16 + lr) << 7) + (kc << 6) + (lg << 4);
                s16x8 ap = *(const s16x8*)(PwB + (ro ^ swz));
#pragma unroll
                for (int df = 0; df < 4; ++df)
                    acco[mi][df] = mfma16(ap, bv[kc][df], acco[mi][df]);
                accl[mi] = mfma16(ap, ones, accl[mi]);
            }
        __builtin_amdgcn_s_setprio(0);
    }

    // ---- intra-block combine: wave1 -> LDS, wave0 adds + normalizes + stores ----
    float* ob = (float*)&Pbuf[0][0];   // 32x64 f32 = 8KB (both P buffers, now dead)
    __syncthreads();
    if (wid == 1) {
#pragma unroll
        for (int mi = 0; mi < 2; ++mi) {
#pragma unroll
            for (int df = 0; df < 4; ++df)
#pragma unroll
                for (int r = 0; r < 4; ++r)
                    ob[(mi * 16 + lg * 4 + r) * 64 + df * 16 + lr] = acco[mi][df][r];
            if (lr == 0)
#pragma unroll
                for (int r = 0; r < 4; ++r)
                    lbuf[mi * 16 + lg * 4 + r] = accl[mi][r];
        }
    }
    __syncthreads();
    if (wid == 0) {
        const int b = bh >> 4, h = bh & 15;
#pragma unroll
        for (int mi = 0; mi < 2; ++mi) {
            float inv[4];
#pragma unroll
            for (int r = 0; r < 4; ++r)
                inv[r] = 1.0f / (accl[mi][r] + lbuf[mi * 16 + lg * 4 + r]);
#pragma unroll
            for (int df = 0; df < 4; ++df)
#pragma unroll
                for (int r = 0; r < 4; ++r) {
                    const int s = q0 + mi * 16 + lg * 4 + r;
                    const int d = df * 16 + lr;
                    float val = acco[mi][df][r] + ob[(mi * 16 + lg * 4 + r) * 64 + d];
                    O[(((int64_t)(b * 2048 + s)) * 16 + h) * 64 + d] = f2b(val * inv[r]);
                }
        }
    }
}

// ---------------- output projection GEMM: M=4096, N=1024, fp32 out ----------------
__global__ void __launch_bounds__(256)
k_gemm_out(const u16* __restrict__ Ob, const u16* __restrict__ wob, float* __restrict__ out) {
    __shared__ u16 As[4096], Bs[4096];
    int m0 = blockIdx.x * 128, n0 = blockIdx.y * 128;
    f32x4 acc[4][4];
    gemm128_loop(Ob, wob, m0, n0, As, Bs, acc);
    const int lane = threadIdx.x & 63, wid = threadIdx.x >> 6;
    const int wm = (wid >> 1) << 6, wn = (wid & 1) << 6;
    const int lr = lane & 15, lg = lane >> 4;
#pragma unroll
    for (int mi = 0; mi < 4; mi++)
#pragma unroll
        for (int ni = 0; ni < 4; ni++) {
            int gn = n0 + wn + ni * 16 + lr;
#pragma unroll
            for (int r = 0; r < 4; r++) {
                int gm = m0 + wm + mi * 16 + lg * 4 + r;
                out[(int64_t)gm * 1024 + gn] = acc[mi][ni][r];
            }
        }
}

extern "C" void kernel_launch(void* const* d_in, const int* in_sizes, int n_in,
                              void* d_out, int out_size, void* d_ws, size_t ws_size,
                              hipStream_t stream) {
    const float* x  = (const float*)d_in[0];
    const int* pos  = (const int*)d_in[1];
    const float* wq = (const float*)d_in[2];
    const float* wk = (const float*)d_in[3];
    const float* wv = (const float*)d_in[4];
    const float* wo = (const float*)d_in[5];
    float* out = (float*)d_out;

    char* w = (char*)d_ws;
    u16* xb    = (u16*)w;    w += (size_t)MROWS * DM * 2;        // 8 MB
    u16* wqkvb = (u16*)w;    w += (size_t)3 * DM * DM * 2;       // 6 MB
    u16* wob   = (u16*)w;    w += (size_t)DM * DM * 2;           // 2 MB
    float2* tab = (float2*)w; w += (size_t)SS * 32 * sizeof(float2); // 512 KB
    u16* Qb = (u16*)w;       w += (size_t)MROWS * DM * 2;        // 8 MB
    u16* Kb = (u16*)w;       w += (size_t)MROWS * DM * 2;        // 8 MB
    u16* Vt = (u16*)w;       w += (size_t)MROWS * DM * 2;        // 8 MB
    u16* Ob = (u16*)w;                                           // 8 MB

    k_prep<<<dim3(1024), dim3(256), 0, stream>>>(x, wq, wk, wv, wo, xb, wqkvb, wob);
    k_rope_table<<<dim3(256), dim3(256), 0, stream>>>(pos, tab);
    k_gemm_qkv<<<dim3(32, 24), dim3(256), 0, stream>>>(xb, wqkvb, tab, Qb, Kb, Vt);
    k_attn<<<dim3(2048), dim3(128), 0, stream>>>(Qb, Kb, Vt, Ob);
    k_gemm_out<<<dim3(32, 8), dim3(256), 0, stream>>>(Ob, wob, out);
}

// Round 9
// 128.262 us; speedup vs baseline: 3.1791x; 1.1182x over previous
//
#include <hip/hip_runtime.h>
#include <hip/hip_bf16.h>

// Problem constants
#define DM    1024
#define NH    16
#define DKH   64
#define BB    2
#define SS    2048
#define MROWS (BB*SS)   // 4096

typedef __attribute__((ext_vector_type(8))) short s16x8;
typedef __attribute__((ext_vector_type(4))) float f32x4;
typedef unsigned short u16;

#if __has_builtin(__builtin_amdgcn_exp2f)
#define EXP2(x) __builtin_amdgcn_exp2f(x)
#else
#define EXP2(x) exp2f(x)
#endif

__device__ inline u16 f2b(float f) {
    __hip_bfloat16 h = __float2bfloat16(f);
    return __builtin_bit_cast(u16, h);
}
__device__ inline float b2f(u16 u) {
    return __bfloat162float(__builtin_bit_cast(__hip_bfloat16, u));
}

__device__ inline f32x4 mfma16(s16x8 a, s16x8 b, f32x4 c) {
    return __builtin_amdgcn_mfma_f32_16x16x32_bf16(a, b, c, 0, 0, 0);
}

__device__ inline void gload_lds16(const u16* g, u16* l) {
    __builtin_amdgcn_global_load_lds((const __attribute__((address_space(1))) void*)g,
                                     (__attribute__((address_space(3))) void*)l, 16, 0, 0);
}

// ---------------- prep: fp32 -> bf16 casts ----------------
__global__ void k_prep(const float* __restrict__ x, const float* __restrict__ wq,
                       const float* __restrict__ wk, const float* __restrict__ wv,
                       const float* __restrict__ wo,
                       u16* __restrict__ xb, u16* __restrict__ wqkvb, u16* __restrict__ wob) {
    int64_t i0 = (int64_t)blockIdx.x * blockDim.x + threadIdx.x;
    int64_t strd = (int64_t)gridDim.x * blockDim.x;
    const float4* x4 = (const float4*)x;
    ushort4* xb4 = (ushort4*)xb;
    for (int64_t t = i0; t < (int64_t)MROWS*DM/4; t += strd) {
        float4 v = x4[t];
        xb4[t] = make_ushort4(f2b(v.x), f2b(v.y), f2b(v.z), f2b(v.w));
    }
    const float4* q4 = (const float4*)wq;
    const float4* k4 = (const float4*)wk;
    const float4* v4 = (const float4*)wv;
    const float4* o4 = (const float4*)wo;
    ushort4* w4  = (ushort4*)wqkvb;
    ushort4* wo4 = (ushort4*)wob;
    const int64_t nw4 = (int64_t)DM*DM/4;   // 262144
    for (int64_t t = i0; t < nw4; t += strd) {
        float4 a = q4[t]; w4[t]         = make_ushort4(f2b(a.x), f2b(a.y), f2b(a.z), f2b(a.w));
        float4 b = k4[t]; w4[nw4 + t]   = make_ushort4(f2b(b.x), f2b(b.y), f2b(b.z), f2b(b.w));
        float4 c = v4[t]; w4[2*nw4 + t] = make_ushort4(f2b(c.x), f2b(c.y), f2b(c.z), f2b(c.w));
        float4 d = o4[t]; wo4[t]        = make_ushort4(f2b(d.x), f2b(d.y), f2b(d.z), f2b(d.w));
    }
}

// ---------------- RoPE cos/sin table ----------------
__global__ void k_rope_table(const int* __restrict__ pos, float2* __restrict__ tab) {
    int i = blockIdx.x * blockDim.x + threadIdx.x;  // SS*32 = 65536
    if (i >= SS * 32) return;
    int s = i >> 5, j = i & 31;
    float p = (float)pos[s];
    float freq = powf(10000.0f, -(float)(2 * j) * (1.0f / 64.0f));
    float a = p * freq;
    tab[i] = make_float2(cosf(a), sinf(a));
}

// ---------------- shared 128x128 GEMM mainloop (K=1024, B^T operand) ----------------
__device__ inline void gemm128_loop(const u16* __restrict__ A, const u16* __restrict__ Bt,
                                    int m0, int n0, u16* As, u16* Bs, f32x4 acc[4][4]) {
    const int tid  = threadIdx.x;
    const int lane = tid & 63;
    const int wid  = tid >> 6;
    const int wm = (wid >> 1) << 6;
    const int wn = (wid & 1) << 6;
    const int lr = lane & 15;
    const int lk = (lane >> 4) << 3;

#pragma unroll
    for (int mi = 0; mi < 4; mi++)
#pragma unroll
        for (int ni = 0; ni < 4; ni++) acc[mi][ni] = f32x4{0.f, 0.f, 0.f, 0.f};

    for (int k0 = 0; k0 < 1024; k0 += 32) {
#pragma unroll
        for (int iss = 0; iss < 2; ++iss) {
            int idx = iss * 2048 + tid * 8;
            int row = idx >> 5;
            int col = idx & 31;
            gload_lds16(A  + (int64_t)(m0 + row) * 1024 + (k0 + col), As + idx);
            gload_lds16(Bt + (int64_t)(n0 + row) * 1024 + (k0 + col), Bs + idx);
        }
        __syncthreads();
        s16x8 af[4], bf[4];
#pragma unroll
        for (int mi = 0; mi < 4; mi++)
            af[mi] = *(const s16x8*)(As + (wm + mi * 16 + lr) * 32 + lk);
#pragma unroll
        for (int ni = 0; ni < 4; ni++)
            bf[ni] = *(const s16x8*)(Bs + (wn + ni * 16 + lr) * 32 + lk);
#pragma unroll
        for (int mi = 0; mi < 4; mi++)
#pragma unroll
            for (int ni = 0; ni < 4; ni++)
                acc[mi][ni] = mfma16(af[mi], bf[ni], acc[mi][ni]);
        __syncthreads();
    }
}

// ---------------- QKV projection GEMM with fused RoPE + V-transpose epilogue ----------------
__global__ void __launch_bounds__(256)
k_gemm_qkv(const u16* __restrict__ xb, const u16* __restrict__ wqkvb,
           const float2* __restrict__ tab,
           u16* __restrict__ Qb, u16* __restrict__ Kb, u16* __restrict__ Vt) {
    __shared__ u16 As[4096], Bs[4096];
    int m0 = blockIdx.x * 128, n0 = blockIdx.y * 128;
    f32x4 acc[4][4];
    gemm128_loop(xb, wqkvb, m0, n0, As, Bs, acc);
    const float QSC = 0.18033688011112042f;  // (1/8) * log2(e)
    const int lane = threadIdx.x & 63, wid = threadIdx.x >> 6;
    const int wm = (wid >> 1) << 6, wn = (wid & 1) << 6;
    const int lr = lane & 15, lg = lane >> 4;
    const bool evenlane = (lr & 1) == 0;
#pragma unroll
    for (int mi = 0; mi < 4; mi++) {
        const int gm0 = m0 + wm + mi * 16 + lg * 4;
        const int b = gm0 >> 11;
        const int s0 = gm0 & 2047;
#pragma unroll
        for (int ni = 0; ni < 4; ni++) {
            int gn = n0 + wn + ni * 16 + lr;
            int which = gn >> 10;
            int nn = gn & 1023;
            int h = nn >> 6, d = nn & 63;
            if (which == 2) {
                ushort4 pk;
                pk.x = f2b(acc[mi][ni][0]);
                pk.y = f2b(acc[mi][ni][1]);
                pk.z = f2b(acc[mi][ni][2]);
                pk.w = f2b(acc[mi][ni][3]);
                *(ushort4*)(Vt + ((int64_t)(b * 16 + h)) * (2048 * 64)
                               + (int64_t)d * 2048 + s0) = pk;
            } else {
                u16* dst = (which == 0) ? Qb : Kb;
                float scl = (which == 0) ? QSC : 1.0f;
                int j = d >> 1;
#pragma unroll
                for (int r = 0; r < 4; r++) {
                    float v = acc[mi][ni][r];
                    float partner = __shfl_xor(v, 1, 64);
                    float2 cs = tab[(s0 + r) * 32 + j];
                    float outv = evenlane ? (cs.x * v - cs.y * partner)
                                          : (cs.y * partner + cs.x * v);
                    dst[(((int64_t)(b * 16 + h)) * 2048 + (s0 + r)) * 64 + d] =
                        f2b(outv * scl);
                }
            }
        }
    }
}

// ---------------- causal flash attention, LDS-staged K/V (m214-style block) ----------
// 4 waves/block own 128 q-rows (wave w: rows chunk*128 + w*32 ..+31).
// K/V 64-key tiles staged global->LDS via global_load_lds, double-buffered,
// prefetch t+1 issued before compute t; 16B-XOR swizzle (pre-swizzled source +
// swizzled reads) kills the stride-128B 16-way bank conflict.
// Max-free exp2 softmax; per-wave P in LDS; ones-MFMA rowsum; direct store.
// Chunk pairing (G<8 -> 15-G else G-8) gives each CU's 2 blocks a constant
// 34-tile total.
__global__ void __launch_bounds__(256)
k_attn(const u16* __restrict__ Q, const u16* __restrict__ K,
       const u16* __restrict__ Vt, u16* __restrict__ O) {
    __shared__ __align__(16) u16 Kl[2][4096];   // 64 keys x 64 d, swizzled
    __shared__ __align__(16) u16 Vl[2][4096];   // 64 d x 64 keys, swizzled
    __shared__ __align__(16) char Pbuf[4][4096];
    const int tid  = threadIdx.x;
    const int lane = tid & 63;
    const int wid  = tid >> 6;
    const int lr = lane & 15;
    const int lg = lane >> 4;
    const int lk = lg * 8;
    const int G  = blockIdx.x >> 5;
    const int bh = blockIdx.x & 31;             // bh -> XCD bh%8
    const int chunk = (G < 8) ? (15 - G) : (G - 8);
    const int q0 = chunk * 128 + wid * 32;      // this wave's first q row
    const int T  = 2 * chunk + 2;               // tiles staged by the block
    const int Tw = (q0 + 31) >> 6;              // this wave's last (diagonal) tile
    const int64_t base = (int64_t)bh * (2048 * 64);
    const u16* Qp = Q  + base;
    const u16* Kp = K  + base;
    const u16* Vp = Vt + base;   // [d][s] layout

    // Q fragments (already scaled by 0.125*log2e in rope)
    s16x8 aq[2][2];
#pragma unroll
    for (int mi = 0; mi < 2; ++mi)
#pragma unroll
        for (int db = 0; db < 2; ++db)
            aq[mi][db] = *(const s16x8*)(Qp + (q0 + mi * 16 + lr) * 64 + db * 32 + lk);

    f32x4 acco[2][4];
    f32x4 accl[2];
#pragma unroll
    for (int mi = 0; mi < 2; ++mi) {
        accl[mi] = f32x4{0.f, 0.f, 0.f, 0.f};
#pragma unroll
        for (int df = 0; df < 4; ++df) acco[mi][df] = f32x4{0.f, 0.f, 0.f, 0.f};
    }
    const s16x8 ones = {(short)0x3F80, (short)0x3F80, (short)0x3F80, (short)0x3F80,
                        (short)0x3F80, (short)0x3F80, (short)0x3F80, (short)0x3F80};
    const int swz = (lr & 7) << 4;
    char* PwB = &Pbuf[wid][0];

    // stage tile t into buffer bb: linear LDS dest, inverse-swizzled global source
#define STAGE(t, bb)                                                           \
    {                                                                          \
        const u16* ks = Kp + (t) * 4096;   /* key rows, 64 elems each */       \
        const u16* vs = Vp + (t) * 64;     /* d rows, stride 2048 */           \
        _Pragma("unroll")                                                      \
        for (int p = 0; p < 2; ++p) {                                          \
            int o = p * 4096 + tid * 16;   /* byte offset in 8KB tile */       \
            int row = o >> 7;                                                  \
            int cc = ((o >> 4) & 7) ^ (row & 7);                               \
            gload_lds16(ks + row * 64 + cc * 8,                                \
                        (u16*)((char*)&Kl[bb][0] + o));                        \
            gload_lds16(vs + row * 2048 + cc * 8,                              \
                        (u16*)((char*)&Vl[bb][0] + o));                        \
        }                                                                      \
    }

    STAGE(0, 0)
    asm volatile("s_waitcnt vmcnt(0)" ::: "memory");
    __syncthreads();

    for (int t = 0; t < T; ++t) {
        const int cur = t & 1;
        if (t + 1 < T) STAGE(t + 1, cur ^ 1)
        if (t <= Tw) {
            const char* Kc = (const char*)&Kl[cur][0];
            const char* Vc = (const char*)&Vl[cur][0];
            // K fragments from LDS (swizzled)
            s16x8 bk[4][2];
#pragma unroll
            for (int kb = 0; kb < 4; ++kb)
#pragma unroll
                for (int db = 0; db < 2; ++db) {
                    int row = kb * 16 + lr;
                    int cc = (db * 4 + lg) ^ (row & 7);
                    bk[kb][db] = *(const s16x8*)(Kc + row * 128 + cc * 16);
                }
            // QK^T
            f32x4 sc[2][4];
            __builtin_amdgcn_s_setprio(1);
#pragma unroll
            for (int mi = 0; mi < 2; ++mi)
#pragma unroll
                for (int kb = 0; kb < 4; ++kb) {
                    sc[mi][kb] = f32x4{0.f, 0.f, 0.f, 0.f};
#pragma unroll
                    for (int db = 0; db < 2; ++db)
                        sc[mi][kb] = mfma16(aq[mi][db], bk[kb][db], sc[mi][kb]);
                }
            __builtin_amdgcn_s_setprio(0);
            // exp2 + P write (mask only on this wave's diagonal tile)
            const int k0 = t << 6;
            if (t == Tw) {
#pragma unroll
                for (int mi = 0; mi < 2; ++mi)
#pragma unroll
                    for (int kb = 0; kb < 4; ++kb)
#pragma unroll
                        for (int r = 0; r < 4; ++r) {
                            int ql = mi * 16 + lg * 4 + r;
                            int kg = k0 + kb * 16 + lr;
                            float sv = (kg <= q0 + ql) ? sc[mi][kb][r] : -3.0e38f;
                            float pp = EXP2(sv);
                            int bo = (ql << 7) + ((kb * 16 + lr) << 1);
                            *(u16*)(PwB + (bo ^ ((ql & 7) << 4))) = f2b(pp);
                        }
            } else {
#pragma unroll
                for (int mi = 0; mi < 2; ++mi)
#pragma unroll
                    for (int kb = 0; kb < 4; ++kb)
#pragma unroll
                        for (int r = 0; r < 4; ++r) {
                            int ql = mi * 16 + lg * 4 + r;
                            float pp = EXP2(sc[mi][kb][r]);
                            int bo = (ql << 7) + ((kb * 16 + lr) << 1);
                            *(u16*)(PwB + (bo ^ ((ql & 7) << 4))) = f2b(pp);
                        }
            }
            // V fragments from LDS (swizzled)
            s16x8 bv[2][4];
#pragma unroll
            for (int kc = 0; kc < 2; ++kc)
#pragma unroll
                for (int df = 0; df < 4; ++df) {
                    int row = df * 16 + lr;
                    int cc = (kc * 4 + lg) ^ (row & 7);
                    bv[kc][df] = *(const s16x8*)(Vc + row * 128 + cc * 16);
                }
            asm volatile("s_waitcnt lgkmcnt(0)" ::: "memory");
            // PV + row-sum via all-ones MFMA
            __builtin_amdgcn_s_setprio(1);
#pragma unroll
            for (int mi = 0; mi < 2; ++mi)
#pragma unroll
                for (int kc = 0; kc < 2; ++kc) {
                    int ro = ((mi * 16 + lr) << 7) + (kc << 6) + (lg << 4);
                    s16x8 ap = *(const s16x8*)(PwB + (ro ^ swz));
#pragma unroll
                    for (int df = 0; df < 4; ++df)
                        acco[mi][df] = mfma16(ap, bv[kc][df], acco[mi][df]);
                    accl[mi] = mfma16(ap, ones, accl[mi]);
                }
            __builtin_amdgcn_s_setprio(0);
        }
        if (t + 1 < T) asm volatile("s_waitcnt vmcnt(0)" ::: "memory");
        __syncthreads();
    }
#undef STAGE

    // ---- epilogue: every wave stores its own 32 rows ----
    const int b = bh >> 4, h = bh & 15;
#pragma unroll
    for (int mi = 0; mi < 2; ++mi) {
        float inv[4];
#pragma unroll
        for (int r = 0; r < 4; ++r) inv[r] = 1.0f / accl[mi][r];
#pragma unroll
        for (int df = 0; df < 4; ++df)
#pragma unroll
            for (int r = 0; r < 4; ++r) {
                const int s = q0 + mi * 16 + lg * 4 + r;
                const int d = df * 16 + lr;
                O[(((int64_t)(b * 2048 + s)) * 16 + h) * 64 + d] = f2b(acco[mi][df][r] * inv[r]);
            }
    }
}

// ---------------- output projection GEMM: M=4096, N=1024, fp32 out ----------------
__global__ void __launch_bounds__(256)
k_gemm_out(const u16* __restrict__ Ob, const u16* __restrict__ wob, float* __restrict__ out) {
    __shared__ u16 As[4096], Bs[4096];
    int m0 = blockIdx.x * 128, n0 = blockIdx.y * 128;
    f32x4 acc[4][4];
    gemm128_loop(Ob, wob, m0, n0, As, Bs, acc);
    const int lane = threadIdx.x & 63, wid = threadIdx.x >> 6;
    const int wm = (wid >> 1) << 6, wn = (wid & 1) << 6;
    const int lr = lane & 15, lg = lane >> 4;
#pragma unroll
    for (int mi = 0; mi < 4; mi++)
#pragma unroll
        for (int ni = 0; ni < 4; ni++) {
            int gn = n0 + wn + ni * 16 + lr;
#pragma unroll
            for (int r = 0; r < 4; r++) {
                int gm = m0 + wm + mi * 16 + lg * 4 + r;
                out[(int64_t)gm * 1024 + gn] = acc[mi][ni][r];
            }
        }
}

extern "C" void kernel_launch(void* const* d_in, const int* in_sizes, int n_in,
                              void* d_out, int out_size, void* d_ws, size_t ws_size,
                              hipStream_t stream) {
    const float* x  = (const float*)d_in[0];
    const int* pos  = (const int*)d_in[1];
    const float* wq = (const float*)d_in[2];
    const float* wk = (const float*)d_in[3];
    const float* wv = (const float*)d_in[4];
    const float* wo = (const float*)d_in[5];
    float* out = (float*)d_out;

    char* w = (char*)d_ws;
    u16* xb    = (u16*)w;    w += (size_t)MROWS * DM * 2;        // 8 MB
    u16* wqkvb = (u16*)w;    w += (size_t)3 * DM * DM * 2;       // 6 MB
    u16* wob   = (u16*)w;    w += (size_t)DM * DM * 2;           // 2 MB
    float2* tab = (float2*)w; w += (size_t)SS * 32 * sizeof(float2); // 512 KB
    u16* Qb = (u16*)w;       w += (size_t)MROWS * DM * 2;        // 8 MB
    u16* Kb = (u16*)w;       w += (size_t)MROWS * DM * 2;        // 8 MB
    u16* Vt = (u16*)w;       w += (size_t)MROWS * DM * 2;        // 8 MB
    u16* Ob = (u16*)w;                                           // 8 MB

    k_prep<<<dim3(1024), dim3(256), 0, stream>>>(x, wq, wk, wv, wo, xb, wqkvb, wob);
    k_rope_table<<<dim3(256), dim3(256), 0, stream>>>(pos, tab);
    k_gemm_qkv<<<dim3(32, 24), dim3(256), 0, stream>>>(xb, wqkvb, tab, Qb, Kb, Vt);
    k_attn<<<dim3(512), dim3(256), 0, stream>>>(Qb, Kb, Vt, Ob);
    k_gemm_out<<<dim3(32, 8), dim3(256), 0, stream>>>(Ob, wob, out);
}

// Round 10
// 123.402 us; speedup vs baseline: 3.3043x; 1.0394x over previous
//
#include <hip/hip_runtime.h>
#include <hip/hip_bf16.h>

// Problem constants
#define DM    1024
#define NH    16
#define DKH   64
#define BB    2
#define SS    2048
#define MROWS (BB*SS)   // 4096

typedef __attribute__((ext_vector_type(8))) short s16x8;
typedef __attribute__((ext_vector_type(4))) float f32x4;
typedef unsigned short u16;

#if __has_builtin(__builtin_amdgcn_exp2f)
#define EXP2(x) __builtin_amdgcn_exp2f(x)
#else
#define EXP2(x) exp2f(x)
#endif

__device__ inline u16 f2b(float f) {
    __hip_bfloat16 h = __float2bfloat16(f);
    return __builtin_bit_cast(u16, h);
}
__device__ inline float b2f(u16 u) {
    return __bfloat162float(__builtin_bit_cast(__hip_bfloat16, u));
}

__device__ inline f32x4 mfma16(s16x8 a, s16x8 b, f32x4 c) {
    return __builtin_amdgcn_mfma_f32_16x16x32_bf16(a, b, c, 0, 0, 0);
}

__device__ inline void gload_lds16(const u16* g, u16* l) {
    __builtin_amdgcn_global_load_lds((const __attribute__((address_space(1))) void*)g,
                                     (__attribute__((address_space(3))) void*)l, 16, 0, 0);
}

// ---------------- prep: fp32 -> bf16 casts ----------------
__global__ void k_prep(const float* __restrict__ x, const float* __restrict__ wq,
                       const float* __restrict__ wk, const float* __restrict__ wv,
                       const float* __restrict__ wo,
                       u16* __restrict__ xb, u16* __restrict__ wqkvb, u16* __restrict__ wob) {
    int64_t i0 = (int64_t)blockIdx.x * blockDim.x + threadIdx.x;
    int64_t strd = (int64_t)gridDim.x * blockDim.x;
    const float4* x4 = (const float4*)x;
    ushort4* xb4 = (ushort4*)xb;
    for (int64_t t = i0; t < (int64_t)MROWS*DM/4; t += strd) {
        float4 v = x4[t];
        xb4[t] = make_ushort4(f2b(v.x), f2b(v.y), f2b(v.z), f2b(v.w));
    }
    const float4* q4 = (const float4*)wq;
    const float4* k4 = (const float4*)wk;
    const float4* v4 = (const float4*)wv;
    const float4* o4 = (const float4*)wo;
    ushort4* w4  = (ushort4*)wqkvb;
    ushort4* wo4 = (ushort4*)wob;
    const int64_t nw4 = (int64_t)DM*DM/4;   // 262144
    for (int64_t t = i0; t < nw4; t += strd) {
        float4 a = q4[t]; w4[t]         = make_ushort4(f2b(a.x), f2b(a.y), f2b(a.z), f2b(a.w));
        float4 b = k4[t]; w4[nw4 + t]   = make_ushort4(f2b(b.x), f2b(b.y), f2b(b.z), f2b(b.w));
        float4 c = v4[t]; w4[2*nw4 + t] = make_ushort4(f2b(c.x), f2b(c.y), f2b(c.z), f2b(c.w));
        float4 d = o4[t]; wo4[t]        = make_ushort4(f2b(d.x), f2b(d.y), f2b(d.z), f2b(d.w));
    }
}

// ---------------- RoPE cos/sin table ----------------
__global__ void k_rope_table(const int* __restrict__ pos, float2* __restrict__ tab) {
    int i = blockIdx.x * blockDim.x + threadIdx.x;  // SS*32 = 65536
    if (i >= SS * 32) return;
    int s = i >> 5, j = i & 31;
    float p = (float)pos[s];
    float freq = powf(10000.0f, -(float)(2 * j) * (1.0f / 64.0f));
    float a = p * freq;
    tab[i] = make_float2(cosf(a), sinf(a));
}

// ---------------- shared 128x128 GEMM mainloop (K=1024, B^T operand) ----------------
__device__ inline void gemm128_loop(const u16* __restrict__ A, const u16* __restrict__ Bt,
                                    int m0, int n0, u16* As, u16* Bs, f32x4 acc[4][4]) {
    const int tid  = threadIdx.x;
    const int lane = tid & 63;
    const int wid  = tid >> 6;
    const int wm = (wid >> 1) << 6;
    const int wn = (wid & 1) << 6;
    const int lr = lane & 15;
    const int lk = (lane >> 4) << 3;

#pragma unroll
    for (int mi = 0; mi < 4; mi++)
#pragma unroll
        for (int ni = 0; ni < 4; ni++) acc[mi][ni] = f32x4{0.f, 0.f, 0.f, 0.f};

    for (int k0 = 0; k0 < 1024; k0 += 32) {
#pragma unroll
        for (int iss = 0; iss < 2; ++iss) {
            int idx = iss * 2048 + tid * 8;
            int row = idx >> 5;
            int col = idx & 31;
            gload_lds16(A  + (int64_t)(m0 + row) * 1024 + (k0 + col), As + idx);
            gload_lds16(Bt + (int64_t)(n0 + row) * 1024 + (k0 + col), Bs + idx);
        }
        __syncthreads();
        s16x8 af[4], bf[4];
#pragma unroll
        for (int mi = 0; mi < 4; mi++)
            af[mi] = *(const s16x8*)(As + (wm + mi * 16 + lr) * 32 + lk);
#pragma unroll
        for (int ni = 0; ni < 4; ni++)
            bf[ni] = *(const s16x8*)(Bs + (wn + ni * 16 + lr) * 32 + lk);
#pragma unroll
        for (int mi = 0; mi < 4; mi++)
#pragma unroll
            for (int ni = 0; ni < 4; ni++)
                acc[mi][ni] = mfma16(af[mi], bf[ni], acc[mi][ni]);
        __syncthreads();
    }
}

// ---------------- QKV projection GEMM with fused RoPE + V-transpose epilogue ----------------
__global__ void __launch_bounds__(256)
k_gemm_qkv(const u16* __restrict__ xb, const u16* __restrict__ wqkvb,
           const float2* __restrict__ tab,
           u16* __restrict__ Qb, u16* __restrict__ Kb, u16* __restrict__ Vt) {
    __shared__ u16 As[4096], Bs[4096];
    int m0 = blockIdx.x * 128, n0 = blockIdx.y * 128;
    f32x4 acc[4][4];
    gemm128_loop(xb, wqkvb, m0, n0, As, Bs, acc);
    const float QSC = 0.18033688011112042f;  // (1/8) * log2(e)
    const int lane = threadIdx.x & 63, wid = threadIdx.x >> 6;
    const int wm = (wid >> 1) << 6, wn = (wid & 1) << 6;
    const int lr = lane & 15, lg = lane >> 4;
    const bool evenlane = (lr & 1) == 0;
#pragma unroll
    for (int mi = 0; mi < 4; mi++) {
        const int gm0 = m0 + wm + mi * 16 + lg * 4;
        const int b = gm0 >> 11;
        const int s0 = gm0 & 2047;
#pragma unroll
        for (int ni = 0; ni < 4; ni++) {
            int gn = n0 + wn + ni * 16 + lr;
            int which = gn >> 10;
            int nn = gn & 1023;
            int h = nn >> 6, d = nn & 63;
            if (which == 2) {
                ushort4 pk;
                pk.x = f2b(acc[mi][ni][0]);
                pk.y = f2b(acc[mi][ni][1]);
                pk.z = f2b(acc[mi][ni][2]);
                pk.w = f2b(acc[mi][ni][3]);
                *(ushort4*)(Vt + ((int64_t)(b * 16 + h)) * (2048 * 64)
                               + (int64_t)d * 2048 + s0) = pk;
            } else {
                u16* dst = (which == 0) ? Qb : Kb;
                float scl = (which == 0) ? QSC : 1.0f;
                int j = d >> 1;
#pragma unroll
                for (int r = 0; r < 4; r++) {
                    float v = acc[mi][ni][r];
                    float partner = __shfl_xor(v, 1, 64);
                    float2 cs = tab[(s0 + r) * 32 + j];
                    float outv = evenlane ? (cs.x * v - cs.y * partner)
                                          : (cs.y * partner + cs.x * v);
                    dst[(((int64_t)(b * 16 + h)) * 2048 + (s0 + r)) * 64 + d] =
                        f2b(outv * scl);
                }
            }
        }
    }
}

// ---------------- causal flash attention, LDS-staged K/V, 2-wave/64-row blocks ----------
// Grid 1024 = 32 chunks x 32 bh; 40KB LDS -> 4 blocks/CU -> 2 waves/SIMD co-resident
// (R9 had 2 blocks/CU decaying to 1 wave/SIMD: 75% exposed latency).
// Both waves compute every staged tile (no dead-wave barriers). LPT + bh->XCD affinity.
__global__ void __launch_bounds__(128)
k_attn(const u16* __restrict__ Q, const u16* __restrict__ K,
       const u16* __restrict__ Vt, u16* __restrict__ O) {
    __shared__ __align__(16) u16 Kl[2][4096];   // 64 keys x 64 d, swizzled
    __shared__ __align__(16) u16 Vl[2][4096];   // 64 d x 64 keys, swizzled
    __shared__ __align__(16) char Pbuf[2][4096];
    const int tid  = threadIdx.x;
    const int lane = tid & 63;
    const int wid  = tid >> 6;                  // 0..1
    const int lr = lane & 15;
    const int lg = lane >> 4;
    const int lk = lg * 8;
    const int G  = blockIdx.x >> 5;             // 0..31
    const int bh = blockIdx.x & 31;             // bh -> XCD bh%8
    const int chunk = 31 - G;                   // LPT: heavy chunks first
    const int q0 = chunk * 64 + wid * 32;       // this wave's first q row
    const int T  = chunk + 1;                   // tiles staged & computed
    const int64_t base = (int64_t)bh * (2048 * 64);
    const u16* Qp = Q  + base;
    const u16* Kp = K  + base;
    const u16* Vp = Vt + base;   // [d][s] layout

    // Q fragments (already scaled by 0.125*log2e in rope)
    s16x8 aq[2][2];
#pragma unroll
    for (int mi = 0; mi < 2; ++mi)
#pragma unroll
        for (int db = 0; db < 2; ++db)
            aq[mi][db] = *(const s16x8*)(Qp + (q0 + mi * 16 + lr) * 64 + db * 32 + lk);

    f32x4 acco[2][4];
    f32x4 accl[2];
#pragma unroll
    for (int mi = 0; mi < 2; ++mi) {
        accl[mi] = f32x4{0.f, 0.f, 0.f, 0.f};
#pragma unroll
        for (int df = 0; df < 4; ++df) acco[mi][df] = f32x4{0.f, 0.f, 0.f, 0.f};
    }
    const s16x8 ones = {(short)0x3F80, (short)0x3F80, (short)0x3F80, (short)0x3F80,
                        (short)0x3F80, (short)0x3F80, (short)0x3F80, (short)0x3F80};
    const int swz = (lr & 7) << 4;
    char* PwB = &Pbuf[wid][0];

    // stage tile t into buffer bb: linear LDS dest, inverse-swizzled global source
    // 128 threads x 16B x 4 = 8KB per array
#define STAGE(t, bb)                                                           \
    {                                                                          \
        const u16* ks = Kp + (t) * 4096;   /* key rows, 64 elems each */       \
        const u16* vs = Vp + (t) * 64;     /* d rows, stride 2048 */           \
        _Pragma("unroll")                                                      \
        for (int p = 0; p < 4; ++p) {                                          \
            int o = p * 2048 + tid * 16;   /* byte offset in 8KB tile */       \
            int row = o >> 7;                                                  \
            int cc = ((o >> 4) & 7) ^ (row & 7);                               \
            gload_lds16(ks + row * 64 + cc * 8,                                \
                        (u16*)((char*)&Kl[bb][0] + o));                        \
            gload_lds16(vs + row * 2048 + cc * 8,                              \
                        (u16*)((char*)&Vl[bb][0] + o));                        \
        }                                                                      \
    }

    STAGE(0, 0)
    asm volatile("s_waitcnt vmcnt(0)" ::: "memory");
    __syncthreads();

    for (int t = 0; t < T; ++t) {
        const int cur = t & 1;
        if (t + 1 < T) STAGE(t + 1, cur ^ 1)
        {
            const char* Kc = (const char*)&Kl[cur][0];
            const char* Vc = (const char*)&Vl[cur][0];
            // K fragments from LDS (swizzled)
            s16x8 bk[4][2];
#pragma unroll
            for (int kb = 0; kb < 4; ++kb)
#pragma unroll
                for (int db = 0; db < 2; ++db) {
                    int row = kb * 16 + lr;
                    int cc = (db * 4 + lg) ^ (row & 7);
                    bk[kb][db] = *(const s16x8*)(Kc + row * 128 + cc * 16);
                }
            // QK^T
            f32x4 sc[2][4];
            __builtin_amdgcn_s_setprio(1);
#pragma unroll
            for (int mi = 0; mi < 2; ++mi)
#pragma unroll
                for (int kb = 0; kb < 4; ++kb) {
                    sc[mi][kb] = f32x4{0.f, 0.f, 0.f, 0.f};
#pragma unroll
                    for (int db = 0; db < 2; ++db)
                        sc[mi][kb] = mfma16(aq[mi][db], bk[kb][db], sc[mi][kb]);
                }
            __builtin_amdgcn_s_setprio(0);
            // exp2 + P write (mask only on the diagonal tile t == T-1)
            const int k0 = t << 6;
            if (t == T - 1) {
#pragma unroll
                for (int mi = 0; mi < 2; ++mi)
#pragma unroll
                    for (int kb = 0; kb < 4; ++kb)
#pragma unroll
                        for (int r = 0; r < 4; ++r) {
                            int ql = mi * 16 + lg * 4 + r;
                            int kg = k0 + kb * 16 + lr;
                            float sv = (kg <= q0 + ql) ? sc[mi][kb][r] : -3.0e38f;
                            float pp = EXP2(sv);
                            int bo = (ql << 7) + ((kb * 16 + lr) << 1);
                            *(u16*)(PwB + (bo ^ ((ql & 7) << 4))) = f2b(pp);
                        }
            } else {
#pragma unroll
                for (int mi = 0; mi < 2; ++mi)
#pragma unroll
                    for (int kb = 0; kb < 4; ++kb)
#pragma unroll
                        for (int r = 0; r < 4; ++r) {
                            int ql = mi * 16 + lg * 4 + r;
                            float pp = EXP2(sc[mi][kb][r]);
                            int bo = (ql << 7) + ((kb * 16 + lr) << 1);
                            *(u16*)(PwB + (bo ^ ((ql & 7) << 4))) = f2b(pp);
                        }
            }
            // V fragments from LDS (swizzled)
            s16x8 bv[2][4];
#pragma unroll
            for (int kc = 0; kc < 2; ++kc)
#pragma unroll
                for (int df = 0; df < 4; ++df) {
                    int row = df * 16 + lr;
                    int cc = (kc * 4 + lg) ^ (row & 7);
                    bv[kc][df] = *(const s16x8*)(Vc + row * 128 + cc * 16);
                }
            asm volatile("s_waitcnt lgkmcnt(0)" ::: "memory");
            // PV + row-sum via all-ones MFMA
            __builtin_amdgcn_s_setprio(1);
#pragma unroll
            for (int mi = 0; mi < 2; ++mi)
#pragma unroll
                for (int kc = 0; kc < 2; ++kc) {
                    int ro = ((mi * 16 + lr) << 7) + (kc << 6) + (lg << 4);
                    s16x8 ap = *(const s16x8*)(PwB + (ro ^ swz));
#pragma unroll
                    for (int df = 0; df < 4; ++df)
                        acco[mi][df] = mfma16(ap, bv[kc][df], acco[mi][df]);
                    accl[mi] = mfma16(ap, ones, accl[mi]);
                }
            __builtin_amdgcn_s_setprio(0);
        }
        if (t + 1 < T) asm volatile("s_waitcnt vmcnt(0)" ::: "memory");
        __syncthreads();
    }
#undef STAGE

    // ---- epilogue: every wave stores its own 32 rows ----
    const int b = bh >> 4, h = bh & 15;
#pragma unroll
    for (int mi = 0; mi < 2; ++mi) {
        float inv[4];
#pragma unroll
        for (int r = 0; r < 4; ++r) inv[r] = 1.0f / accl[mi][r];
#pragma unroll
        for (int df = 0; df < 4; ++df)
#pragma unroll
            for (int r = 0; r < 4; ++r) {
                const int s = q0 + mi * 16 + lg * 4 + r;
                const int d = df * 16 + lr;
                O[(((int64_t)(b * 2048 + s)) * 16 + h) * 64 + d] = f2b(acco[mi][df][r] * inv[r]);
            }
    }
}

// ---------------- output projection GEMM: M=4096, N=1024, fp32 out ----------------
__global__ void __launch_bounds__(256)
k_gemm_out(const u16* __restrict__ Ob, const u16* __restrict__ wob, float* __restrict__ out) {
    __shared__ u16 As[4096], Bs[4096];
    int m0 = blockIdx.x * 128, n0 = blockIdx.y * 128;
    f32x4 acc[4][4];
    gemm128_loop(Ob, wob, m0, n0, As, Bs, acc);
    const int lane = threadIdx.x & 63, wid = threadIdx.x >> 6;
    const int wm = (wid >> 1) << 6, wn = (wid & 1) << 6;
    const int lr = lane & 15, lg = lane >> 4;
#pragma unroll
    for (int mi = 0; mi < 4; mi++)
#pragma unroll
        for (int ni = 0; ni < 4; ni++) {
            int gn = n0 + wn + ni * 16 + lr;
#pragma unroll
            for (int r = 0; r < 4; r++) {
                int gm = m0 + wm + mi * 16 + lg * 4 + r;
                out[(int64_t)gm * 1024 + gn] = acc[mi][ni][r];
            }
        }
}

extern "C" void kernel_launch(void* const* d_in, const int* in_sizes, int n_in,
                              void* d_out, int out_size, void* d_ws, size_t ws_size,
                              hipStream_t stream) {
    const float* x  = (const float*)d_in[0];
    const int* pos  = (const int*)d_in[1];
    const float* wq = (const float*)d_in[2];
    const float* wk = (const float*)d_in[3];
    const float* wv = (const float*)d_in[4];
    const float* wo = (const float*)d_in[5];
    float* out = (float*)d_out;

    char* w = (char*)d_ws;
    u16* xb    = (u16*)w;    w += (size_t)MROWS * DM * 2;        // 8 MB
    u16* wqkvb = (u16*)w;    w += (size_t)3 * DM * DM * 2;       // 6 MB
    u16* wob   = (u16*)w;    w += (size_t)DM * DM * 2;           // 2 MB
    float2* tab = (float2*)w; w += (size_t)SS * 32 * sizeof(float2); // 512 KB
    u16* Qb = (u16*)w;       w += (size_t)MROWS * DM * 2;        // 8 MB
    u16* Kb = (u16*)w;       w += (size_t)MROWS * DM * 2;        // 8 MB
    u16* Vt = (u16*)w;       w += (size_t)MROWS * DM * 2;        // 8 MB
    u16* Ob = (u16*)w;                                           // 8 MB

    k_prep<<<dim3(1024), dim3(256), 0, stream>>>(x, wq, wk, wv, wo, xb, wqkvb, wob);
    k_rope_table<<<dim3(256), dim3(256), 0, stream>>>(pos, tab);
    k_gemm_qkv<<<dim3(32, 24), dim3(256), 0, stream>>>(xb, wqkvb, tab, Qb, Kb, Vt);
    k_attn<<<dim3(1024), dim3(128), 0, stream>>>(Qb, Kb, Vt, Ob);
    k_gemm_out<<<dim3(32, 8), dim3(256), 0, stream>>>(Ob, wob, out);
}

// Round 11
// 114.686 us; speedup vs baseline: 3.5554x; 1.0760x over previous
//
#include <hip/hip_runtime.h>
#include <hip/hip_bf16.h>

// Problem constants
#define DM    1024
#define NH    16
#define DKH   64
#define BB    2
#define SS    2048
#define MROWS (BB*SS)   // 4096

typedef __attribute__((ext_vector_type(8))) short s16x8;
typedef __attribute__((ext_vector_type(4))) float f32x4;
typedef unsigned short u16;

#if __has_builtin(__builtin_amdgcn_exp2f)
#define EXP2(x) __builtin_amdgcn_exp2f(x)
#else
#define EXP2(x) exp2f(x)
#endif

__device__ inline u16 f2b(float f) {
    __hip_bfloat16 h = __float2bfloat16(f);
    return __builtin_bit_cast(u16, h);
}
__device__ inline float b2f(u16 u) {
    return __bfloat162float(__builtin_bit_cast(__hip_bfloat16, u));
}

__device__ inline f32x4 mfma16(s16x8 a, s16x8 b, f32x4 c) {
    return __builtin_amdgcn_mfma_f32_16x16x32_bf16(a, b, c, 0, 0, 0);
}

__device__ inline void gload_lds16(const u16* g, u16* l) {
    __builtin_amdgcn_global_load_lds((const __attribute__((address_space(1))) void*)g,
                                     (__attribute__((address_space(3))) void*)l, 16, 0, 0);
}

// ---------------- prep: fp32 -> bf16 casts ----------------
__global__ void k_prep(const float* __restrict__ x, const float* __restrict__ wq,
                       const float* __restrict__ wk, const float* __restrict__ wv,
                       const float* __restrict__ wo,
                       u16* __restrict__ xb, u16* __restrict__ wqkvb, u16* __restrict__ wob) {
    int64_t i0 = (int64_t)blockIdx.x * blockDim.x + threadIdx.x;
    int64_t strd = (int64_t)gridDim.x * blockDim.x;
    const float4* x4 = (const float4*)x;
    ushort4* xb4 = (ushort4*)xb;
    for (int64_t t = i0; t < (int64_t)MROWS*DM/4; t += strd) {
        float4 v = x4[t];
        xb4[t] = make_ushort4(f2b(v.x), f2b(v.y), f2b(v.z), f2b(v.w));
    }
    const float4* q4 = (const float4*)wq;
    const float4* k4 = (const float4*)wk;
    const float4* v4 = (const float4*)wv;
    const float4* o4 = (const float4*)wo;
    ushort4* w4  = (ushort4*)wqkvb;
    ushort4* wo4 = (ushort4*)wob;
    const int64_t nw4 = (int64_t)DM*DM/4;   // 262144
    for (int64_t t = i0; t < nw4; t += strd) {
        float4 a = q4[t]; w4[t]         = make_ushort4(f2b(a.x), f2b(a.y), f2b(a.z), f2b(a.w));
        float4 b = k4[t]; w4[nw4 + t]   = make_ushort4(f2b(b.x), f2b(b.y), f2b(b.z), f2b(b.w));
        float4 c = v4[t]; w4[2*nw4 + t] = make_ushort4(f2b(c.x), f2b(c.y), f2b(c.z), f2b(c.w));
        float4 d = o4[t]; wo4[t]        = make_ushort4(f2b(d.x), f2b(d.y), f2b(d.z), f2b(d.w));
    }
}

// ---------------- RoPE cos/sin table ----------------
__global__ void k_rope_table(const int* __restrict__ pos, float2* __restrict__ tab) {
    int i = blockIdx.x * blockDim.x + threadIdx.x;  // SS*32 = 65536
    if (i >= SS * 32) return;
    int s = i >> 5, j = i & 31;
    float p = (float)pos[s];
    float freq = powf(10000.0f, -(float)(2 * j) * (1.0f / 64.0f));
    float a = p * freq;
    tab[i] = make_float2(cosf(a), sinf(a));
}

// ---------------- shared 128x128 GEMM mainloop (K=1024, B^T operand) ----------------
__device__ inline void gemm128_loop(const u16* __restrict__ A, const u16* __restrict__ Bt,
                                    int m0, int n0, u16* As, u16* Bs, f32x4 acc[4][4]) {
    const int tid  = threadIdx.x;
    const int lane = tid & 63;
    const int wid  = tid >> 6;
    const int wm = (wid >> 1) << 6;
    const int wn = (wid & 1) << 6;
    const int lr = lane & 15;
    const int lk = (lane >> 4) << 3;

#pragma unroll
    for (int mi = 0; mi < 4; mi++)
#pragma unroll
        for (int ni = 0; ni < 4; ni++) acc[mi][ni] = f32x4{0.f, 0.f, 0.f, 0.f};

    for (int k0 = 0; k0 < 1024; k0 += 32) {
#pragma unroll
        for (int iss = 0; iss < 2; ++iss) {
            int idx = iss * 2048 + tid * 8;
            int row = idx >> 5;
            int col = idx & 31;
            gload_lds16(A  + (int64_t)(m0 + row) * 1024 + (k0 + col), As + idx);
            gload_lds16(Bt + (int64_t)(n0 + row) * 1024 + (k0 + col), Bs + idx);
        }
        __syncthreads();
        s16x8 af[4], bf[4];
#pragma unroll
        for (int mi = 0; mi < 4; mi++)
            af[mi] = *(const s16x8*)(As + (wm + mi * 16 + lr) * 32 + lk);
#pragma unroll
        for (int ni = 0; ni < 4; ni++)
            bf[ni] = *(const s16x8*)(Bs + (wn + ni * 16 + lr) * 32 + lk);
#pragma unroll
        for (int mi = 0; mi < 4; mi++)
#pragma unroll
            for (int ni = 0; ni < 4; ni++)
                acc[mi][ni] = mfma16(af[mi], bf[ni], acc[mi][ni]);
        __syncthreads();
    }
}

// ---------------- QKV projection GEMM with fused RoPE + V-transpose epilogue ----------------
__global__ void __launch_bounds__(256)
k_gemm_qkv(const u16* __restrict__ xb, const u16* __restrict__ wqkvb,
           const float2* __restrict__ tab,
           u16* __restrict__ Qb, u16* __restrict__ Kb, u16* __restrict__ Vt) {
    __shared__ u16 As[4096], Bs[4096];
    int m0 = blockIdx.x * 128, n0 = blockIdx.y * 128;
    f32x4 acc[4][4];
    gemm128_loop(xb, wqkvb, m0, n0, As, Bs, acc);
    const float QSC = 0.18033688011112042f;  // (1/8) * log2(e)
    const int lane = threadIdx.x & 63, wid = threadIdx.x >> 6;
    const int wm = (wid >> 1) << 6, wn = (wid & 1) << 6;
    const int lr = lane & 15, lg = lane >> 4;
    const bool evenlane = (lr & 1) == 0;
#pragma unroll
    for (int mi = 0; mi < 4; mi++) {
        const int gm0 = m0 + wm + mi * 16 + lg * 4;
        const int b = gm0 >> 11;
        const int s0 = gm0 & 2047;
#pragma unroll
        for (int ni = 0; ni < 4; ni++) {
            int gn = n0 + wn + ni * 16 + lr;
            int which = gn >> 10;
            int nn = gn & 1023;
            int h = nn >> 6, d = nn & 63;
            if (which == 2) {
                ushort4 pk;
                pk.x = f2b(acc[mi][ni][0]);
                pk.y = f2b(acc[mi][ni][1]);
                pk.z = f2b(acc[mi][ni][2]);
                pk.w = f2b(acc[mi][ni][3]);
                *(ushort4*)(Vt + ((int64_t)(b * 16 + h)) * (2048 * 64)
                               + (int64_t)d * 2048 + s0) = pk;
            } else {
                u16* dst = (which == 0) ? Qb : Kb;
                float scl = (which == 0) ? QSC : 1.0f;
                int j = d >> 1;
#pragma unroll
                for (int r = 0; r < 4; r++) {
                    float v = acc[mi][ni][r];
                    float partner = __shfl_xor(v, 1, 64);
                    float2 cs = tab[(s0 + r) * 32 + j];
                    float outv = evenlane ? (cs.x * v - cs.y * partner)
                                          : (cs.y * partner + cs.x * v);
                    dst[(((int64_t)(b * 16 + h)) * 2048 + (s0 + r)) * 64 + d] =
                        f2b(outv * scl);
                }
            }
        }
    }
}

// ---------------- causal flash attention, LDS-staged K/V, balanced split-KV ----------
// 48 work-units per bh: chunks 0-15 -> 1 block (all tiles); chunks 16-31 -> 2 blocks
// (seg0 = first half of KV tiles, seg1 = rest incl. diagonal). Every block <= 16
// serial tiles (R10's critical path was the lone 32-tile block in a dead-tail GPU).
// Split partials are UNNORMALIZED bf16 O + f32 l written to disjoint addresses
// (no atomics); k_combine merges. LPT ordering + bh->XCD affinity (low 5 bits).
__global__ void __launch_bounds__(128)
k_attn(const u16* __restrict__ Q, const u16* __restrict__ K,
       const u16* __restrict__ Vt, u16* __restrict__ O,
       u16* __restrict__ Op1, float* __restrict__ l0, float* __restrict__ l1) {
    __shared__ __align__(16) u16 Kl[2][4096];   // 64 keys x 64 d, swizzled
    __shared__ __align__(16) u16 Vl[2][4096];   // 64 d x 64 keys, swizzled
    __shared__ __align__(16) char Pbuf[2][4096];
    const int tid  = threadIdx.x;
    const int lane = tid & 63;
    const int wid  = tid >> 6;                  // 0..1
    const int lr = lane & 15;
    const int lg = lane >> 4;
    const int lk = lg * 8;
    const int G  = blockIdx.x >> 5;             // 0..47
    const int bh = blockIdx.x & 31;             // bh -> XCD bh%8
    // LPT unit map: G<8: chunks 15..8 unsplit; G<40: chunks 31..16 split x2; else 7..0
    int c, seg, split;
    if (G < 8)       { c = 15 - G;            seg = 0;     split = 0; }
    else if (G < 40) { int j = G - 8; c = 31 - (j >> 1); seg = j & 1; split = 1; }
    else             { c = 47 - G;            seg = 0;     split = 0; }
    const int T  = c + 1;                       // total tiles for this chunk
    const int h0 = T >> 1;
    const int t0 = (split && seg == 1) ? h0 : 0;
    const int nT = split ? (seg == 0 ? h0 : T - h0) : T;
    const int hasDiag = !(split && seg == 0);
    const int q0 = c * 64 + wid * 32;           // this wave's first q row
    const int64_t base = (int64_t)bh * (2048 * 64);
    const u16* Qp = Q  + base;
    const u16* Kp = K  + base;
    const u16* Vp = Vt + base;   // [d][s] layout

    // Q fragments (already scaled by 0.125*log2e in rope)
    s16x8 aq[2][2];
#pragma unroll
    for (int mi = 0; mi < 2; ++mi)
#pragma unroll
        for (int db = 0; db < 2; ++db)
            aq[mi][db] = *(const s16x8*)(Qp + (q0 + mi * 16 + lr) * 64 + db * 32 + lk);

    f32x4 acco[2][4];
    f32x4 accl[2];
#pragma unroll
    for (int mi = 0; mi < 2; ++mi) {
        accl[mi] = f32x4{0.f, 0.f, 0.f, 0.f};
#pragma unroll
        for (int df = 0; df < 4; ++df) acco[mi][df] = f32x4{0.f, 0.f, 0.f, 0.f};
    }
    const s16x8 ones = {(short)0x3F80, (short)0x3F80, (short)0x3F80, (short)0x3F80,
                        (short)0x3F80, (short)0x3F80, (short)0x3F80, (short)0x3F80};
    const int swz = (lr & 7) << 4;
    char* PwB = &Pbuf[wid][0];

#define STAGE(t, bb)                                                           \
    {                                                                          \
        const u16* ks = Kp + (t) * 4096;                                       \
        const u16* vs = Vp + (t) * 64;                                         \
        _Pragma("unroll")                                                      \
        for (int p = 0; p < 4; ++p) {                                          \
            int o = p * 2048 + tid * 16;                                       \
            int row = o >> 7;                                                  \
            int cc = ((o >> 4) & 7) ^ (row & 7);                               \
            gload_lds16(ks + row * 64 + cc * 8,                                \
                        (u16*)((char*)&Kl[bb][0] + o));                        \
            gload_lds16(vs + row * 2048 + cc * 8,                              \
                        (u16*)((char*)&Vl[bb][0] + o));                        \
        }                                                                      \
    }

    STAGE(t0, 0)
    asm volatile("s_waitcnt vmcnt(0)" ::: "memory");
    __syncthreads();

    for (int u = 0; u < nT; ++u) {
        const int t = t0 + u;
        const int cur = u & 1;
        if (u + 1 < nT) STAGE(t0 + u + 1, cur ^ 1)
        {
            const char* Kc = (const char*)&Kl[cur][0];
            const char* Vc = (const char*)&Vl[cur][0];
            // K fragments from LDS (swizzled)
            s16x8 bk[4][2];
#pragma unroll
            for (int kb = 0; kb < 4; ++kb)
#pragma unroll
                for (int db = 0; db < 2; ++db) {
                    int row = kb * 16 + lr;
                    int cc = (db * 4 + lg) ^ (row & 7);
                    bk[kb][db] = *(const s16x8*)(Kc + row * 128 + cc * 16);
                }
            // QK^T
            f32x4 sc[2][4];
            __builtin_amdgcn_s_setprio(1);
#pragma unroll
            for (int mi = 0; mi < 2; ++mi)
#pragma unroll
                for (int kb = 0; kb < 4; ++kb) {
                    sc[mi][kb] = f32x4{0.f, 0.f, 0.f, 0.f};
#pragma unroll
                    for (int db = 0; db < 2; ++db)
                        sc[mi][kb] = mfma16(aq[mi][db], bk[kb][db], sc[mi][kb]);
                }
            __builtin_amdgcn_s_setprio(0);
            // exp2 + P write (mask only on the diagonal tile)
            const int k0 = t << 6;
            if (hasDiag && u == nT - 1) {
#pragma unroll
                for (int mi = 0; mi < 2; ++mi)
#pragma unroll
                    for (int kb = 0; kb < 4; ++kb)
#pragma unroll
                        for (int r = 0; r < 4; ++r) {
                            int ql = mi * 16 + lg * 4 + r;
                            int kg = k0 + kb * 16 + lr;
                            float sv = (kg <= q0 + ql) ? sc[mi][kb][r] : -3.0e38f;
                            float pp = EXP2(sv);
                            int bo = (ql << 7) + ((kb * 16 + lr) << 1);
                            *(u16*)(PwB + (bo ^ ((ql & 7) << 4))) = f2b(pp);
                        }
            } else {
#pragma unroll
                for (int mi = 0; mi < 2; ++mi)
#pragma unroll
                    for (int kb = 0; kb < 4; ++kb)
#pragma unroll
                        for (int r = 0; r < 4; ++r) {
                            int ql = mi * 16 + lg * 4 + r;
                            float pp = EXP2(sc[mi][kb][r]);
                            int bo = (ql << 7) + ((kb * 16 + lr) << 1);
                            *(u16*)(PwB + (bo ^ ((ql & 7) << 4))) = f2b(pp);
                        }
            }
            // V fragments from LDS (swizzled)
            s16x8 bv[2][4];
#pragma unroll
            for (int kc = 0; kc < 2; ++kc)
#pragma unroll
                for (int df = 0; df < 4; ++df) {
                    int row = df * 16 + lr;
                    int cc = (kc * 4 + lg) ^ (row & 7);
                    bv[kc][df] = *(const s16x8*)(Vc + row * 128 + cc * 16);
                }
            asm volatile("s_waitcnt lgkmcnt(0)" ::: "memory");
            // PV + row-sum via all-ones MFMA
            __builtin_amdgcn_s_setprio(1);
#pragma unroll
            for (int mi = 0; mi < 2; ++mi)
#pragma unroll
                for (int kc = 0; kc < 2; ++kc) {
                    int ro = ((mi * 16 + lr) << 7) + (kc << 6) + (lg << 4);
                    s16x8 ap = *(const s16x8*)(PwB + (ro ^ swz));
#pragma unroll
                    for (int df = 0; df < 4; ++df)
                        acco[mi][df] = mfma16(ap, bv[kc][df], acco[mi][df]);
                    accl[mi] = mfma16(ap, ones, accl[mi]);
                }
            __builtin_amdgcn_s_setprio(0);
        }
        if (u + 1 < nT) asm volatile("s_waitcnt vmcnt(0)" ::: "memory");
        __syncthreads();
    }
#undef STAGE

    // ---- epilogue ----
    const int b = bh >> 4, h = bh & 15;
    if (!split) {
        // final: normalize and store
#pragma unroll
        for (int mi = 0; mi < 2; ++mi) {
            float inv[4];
#pragma unroll
            for (int r = 0; r < 4; ++r) inv[r] = 1.0f / accl[mi][r];
#pragma unroll
            for (int df = 0; df < 4; ++df)
#pragma unroll
                for (int r = 0; r < 4; ++r) {
                    const int s = q0 + mi * 16 + lg * 4 + r;
                    const int d = df * 16 + lr;
                    O[(((int64_t)(b * 2048 + s)) * 16 + h) * 64 + d] =
                        f2b(acco[mi][df][r] * inv[r]);
                }
        }
    } else {
        const int cc = c - 16;
        const int rg0 = (bh * 16 + cc) * 64 + wid * 32;  // row-group base
        if (seg == 0) {
            // unnormalized partial into O's final location + l0
#pragma unroll
            for (int mi = 0; mi < 2; ++mi) {
#pragma unroll
                for (int df = 0; df < 4; ++df)
#pragma unroll
                    for (int r = 0; r < 4; ++r) {
                        const int s = q0 + mi * 16 + lg * 4 + r;
                        const int d = df * 16 + lr;
                        O[(((int64_t)(b * 2048 + s)) * 16 + h) * 64 + d] =
                            f2b(acco[mi][df][r]);
                    }
                if (lr == 0)
#pragma unroll
                    for (int r = 0; r < 4; ++r)
                        l0[rg0 + mi * 16 + lg * 4 + r] = accl[mi][r];
            }
        } else {
            // unnormalized partial into scratch + l1
#pragma unroll
            for (int mi = 0; mi < 2; ++mi) {
#pragma unroll
                for (int df = 0; df < 4; ++df)
#pragma unroll
                    for (int r = 0; r < 4; ++r) {
                        const int row = wid * 32 + mi * 16 + lg * 4 + r;
                        const int d = df * 16 + lr;
                        Op1[((int64_t)((bh * 16 + cc) * 64 + row)) * 64 + d] =
                            f2b(acco[mi][df][r]);
                    }
                if (lr == 0)
#pragma unroll
                    for (int r = 0; r < 4; ++r)
                        l1[rg0 + mi * 16 + lg * 4 + r] = accl[mi][r];
            }
        }
    }
}

// ---------------- combine split-KV partials: O = (O + Op1) / (l0 + l1) ----------------
// covers rows s in [1024,2048) of each batch (chunks 16..31)
__global__ void __launch_bounds__(256)
k_combine(u16* __restrict__ O, const u16* __restrict__ Op1,
          const float* __restrict__ l0, const float* __restrict__ l1) {
    int i = blockIdx.x * 256 + threadIdx.x;     // 0..262143
    int rg = i >> 3;                            // (bh,cc,row) 0..32767
    int d0 = (i & 7) << 3;
    int bh = rg >> 10;
    int cc = (rg >> 6) & 15;
    int row = rg & 63;
    float inv = 1.0f / (l0[rg] + l1[rg]);
    int b = bh >> 4, h = bh & 15;
    int s = (16 + cc) * 64 + row;
    u16* op = O + (((int64_t)(b * 2048 + s)) * 16 + h) * 64 + d0;
    const u16* sp = Op1 + (int64_t)rg * 64 + d0;
    s16x8 a = *(const s16x8*)op;
    s16x8 bb = *(const s16x8*)sp;
    u16 outv[8];
#pragma unroll
    for (int j = 0; j < 8; ++j)
        outv[j] = f2b((b2f((u16)a[j]) + b2f((u16)bb[j])) * inv);
    *(s16x8*)op = *(s16x8*)&outv[0];
}

// ---------------- output projection GEMM: M=4096, N=1024, fp32 out ----------------
__global__ void __launch_bounds__(256)
k_gemm_out(const u16* __restrict__ Ob, const u16* __restrict__ wob, float* __restrict__ out) {
    __shared__ u16 As[4096], Bs[4096];
    int m0 = blockIdx.x * 128, n0 = blockIdx.y * 128;
    f32x4 acc[4][4];
    gemm128_loop(Ob, wob, m0, n0, As, Bs, acc);
    const int lane = threadIdx.x & 63, wid = threadIdx.x >> 6;
    const int wm = (wid >> 1) << 6, wn = (wid & 1) << 6;
    const int lr = lane & 15, lg = lane >> 4;
#pragma unroll
    for (int mi = 0; mi < 4; mi++)
#pragma unroll
        for (int ni = 0; ni < 4; ni++) {
            int gn = n0 + wn + ni * 16 + lr;
#pragma unroll
            for (int r = 0; r < 4; r++) {
                int gm = m0 + wm + mi * 16 + lg * 4 + r;
                out[(int64_t)gm * 1024 + gn] = acc[mi][ni][r];
            }
        }
}

extern "C" void kernel_launch(void* const* d_in, const int* in_sizes, int n_in,
                              void* d_out, int out_size, void* d_ws, size_t ws_size,
                              hipStream_t stream) {
    const float* x  = (const float*)d_in[0];
    const int* pos  = (const int*)d_in[1];
    const float* wq = (const float*)d_in[2];
    const float* wk = (const float*)d_in[3];
    const float* wv = (const float*)d_in[4];
    const float* wo = (const float*)d_in[5];
    float* out = (float*)d_out;

    char* w = (char*)d_ws;
    u16* xb    = (u16*)w;    w += (size_t)MROWS * DM * 2;        // 8 MB
    u16* wqkvb = (u16*)w;    w += (size_t)3 * DM * DM * 2;       // 6 MB
    u16* wob   = (u16*)w;    w += (size_t)DM * DM * 2;           // 2 MB
    float2* tab = (float2*)w; w += (size_t)SS * 32 * sizeof(float2); // 512 KB
    u16* Qb = (u16*)w;       w += (size_t)MROWS * DM * 2;        // 8 MB
    u16* Kb = (u16*)w;       w += (size_t)MROWS * DM * 2;        // 8 MB
    u16* Vt = (u16*)w;       w += (size_t)MROWS * DM * 2;        // 8 MB
    u16* Ob = (u16*)w;                                           // 8 MB
    // split-KV scratch carved from xb (dead after k_gemm_qkv): 4MB + 128KB + 128KB
    u16*   Op1 = xb;                                  // 32*16*64*64 bf16 = 4 MB
    float* l0  = (float*)((char*)xb + (4 << 20));     // 128 KB
    float* l1  = (float*)((char*)xb + (4 << 20) + (128 << 10));

    k_prep<<<dim3(1024), dim3(256), 0, stream>>>(x, wq, wk, wv, wo, xb, wqkvb, wob);
    k_rope_table<<<dim3(256), dim3(256), 0, stream>>>(pos, tab);
    k_gemm_qkv<<<dim3(32, 24), dim3(256), 0, stream>>>(xb, wqkvb, tab, Qb, Kb, Vt);
    k_attn<<<dim3(1536), dim3(128), 0, stream>>>(Qb, Kb, Vt, Ob, Op1, l0, l1);
    k_combine<<<dim3(1024), dim3(256), 0, stream>>>(Ob, Op1, l0, l1);
    k_gemm_out<<<dim3(32, 8), dim3(256), 0, stream>>>(Ob, wob, out);
}